// Round 8
// baseline (790.155 us; speedup 1.0000x reference)
//
#include <hip/hip_runtime.h>
#include <math.h>

constexpr int NPTS  = 8192;
constexpr int HIDC  = 128;
constexpr int OUTC2 = 256;
constexpr int PQC   = 512;
constexpr int KK1   = 16;
constexpr int KK2   = 8;

typedef __attribute__((ext_vector_type(8))) short short8;
typedef __attribute__((ext_vector_type(4))) float f32x4;

__device__ __forceinline__ f32x4 mfma16(short8 a, short8 b, f32x4 c) {
  return __builtin_amdgcn_mfma_f32_16x16x32_bf16(a, b, c, 0, 0, 0);
}

// lexicographic (d, idx) insert — for merging lists whose idx order is mixed.
template <int K>
__device__ __forceinline__ void ins_lex(float (&kf)[K], int (&ki)[K], float v, int j) {
  bool ins = (v < kf[K - 1]) || (v == kf[K - 1] && j < ki[K - 1]);
  if (ins) {
    kf[K - 1] = v; ki[K - 1] = j;
    #pragma unroll
    for (int p = K - 1; p > 0; --p) {
      float fa = kf[p - 1], fb = kf[p];
      int   ia = ki[p - 1], ib = ki[p];
      bool sw = (fb < fa) || (fb == fa && ib < ia);
      kf[p - 1] = sw ? fb : fa; ki[p - 1] = sw ? ib : ia;
      kf[p]     = sw ? fa : fb; ki[p]     = sw ? ia : ib;
    }
  }
}

__device__ __forceinline__ unsigned short bf16_rn(float x) {
  unsigned int u = __float_as_uint(x);
  unsigned int r = u + 0x7fffu + ((u >> 16) & 1u);
  return (unsigned short)(r >> 16);
}

__device__ __forceinline__ float rdlane_f(float v, int l) {
  return __int_as_float(__builtin_amdgcn_readlane(__float_as_int(v), l));
}

// ---------------------------------------------------------------- pack x
__global__ void pack_x_kernel(const float* __restrict__ x, float4* __restrict__ x4) {
  int i = blockIdx.x * blockDim.x + threadIdx.x;
  if (i < NPTS) {
    float a = x[3 * i], b = x[3 * i + 1], c = x[3 * i + 2];
    x4[i] = make_float4(a, b, c, a * a + b * b + c * c);
  }
}

// ---------------------------------------------------------------- Wc = [Wl-Wh | Wh] for layer2 stage1
__global__ void prep_w1_kernel(const float* __restrict__ W1, float* __restrict__ Wc) {
  int idx = blockIdx.x * 256 + threadIdx.x;    // 128*512
  int k = idx >> 9, c = idx & 511;
  float wh = W1[(size_t)(HIDC + k) * OUTC2 + (c & 255)];
  Wc[idx] = (c < OUTC2) ? (W1[(size_t)k * OUTC2 + c] - wh) : wh;
}

// ---------------------------------------------------------------- KNN1 (C=3, K=16), ballot-scan
__global__ __launch_bounds__(256) void knn3_kernel(const float4* __restrict__ X4,
                                                   int* __restrict__ idx_out) {
  const int tid  = threadIdx.x;
  const int lane = tid & 63;
  const int wv   = __builtin_amdgcn_readfirstlane(tid >> 6);
  const int half = lane >> 5;           // which query of the wave
  const int l16  = lane & 15;           // list slot
  const bool listlane = (lane & 16) == 0;
  const int q0 = (blockIdx.x * 4 + wv) * 2;

  float qx[2], qy[2], qz[2], qw[2];
  #pragma unroll
  for (int q = 0; q < 2; ++q) {
    float4 v = X4[q0 + q];
    qx[q] = v.x; qy[q] = v.y; qz[q] = v.z; qw[q] = v.w;
  }

  float kd = INFINITY; int kj = 0x7fffffff;
  float wd[2]; int wj[2], ws[2];
  #pragma unroll
  for (int q = 0; q < 2; ++q) { wd[q] = INFINITY; wj[q] = 0x7fffffff; ws[q] = 0; }

  float4 pj = X4[lane];
  for (int j0 = 0; j0 < NPTS; j0 += 64) {
    float4 pjn = pj;
    if (j0 + 64 < NPTS) pjn = X4[j0 + 64 + lane];
    const int j = j0 + lane;
    #pragma unroll
    for (int q = 0; q < 2; ++q) {
      float d = qw[q] + pj.w - 2.f * (qx[q] * pj.x + qy[q] * pj.y + qz[q] * pj.z);
      bool c = (j != q0 + q) && ((d < wd[q]) || (d == wd[q] && j < wj[q]));
      unsigned long long vote = __ballot(c);
      while (vote) {
        const int l = (int)__ffsll(vote) - 1;
        vote &= vote - 1;
        const float dv = rdlane_f(d, l);
        const int   jv = j0 + l;
        if ((dv < wd[q]) || (dv == wd[q] && jv < wj[q])) {   // recheck vs CURRENT worst
          const bool mine = (half == q) && listlane && (l16 == ws[q]);
          kd = mine ? dv : kd;
          kj = mine ? jv : kj;
          float av = kd; int aj = kj; int as = l16;
          #pragma unroll
          for (int m = 1; m <= 8; m <<= 1) {
            float ov = __shfl_xor(av, m, 64);
            int   oj = __shfl_xor(aj, m, 64);
            int   os = __shfl_xor(as, m, 64);
            bool g = (ov > av) || (ov == av && oj > aj);
            av = g ? ov : av; aj = g ? oj : aj; as = g ? os : as;
          }
          wd[q] = rdlane_f(av, q * 32);
          wj[q] = __builtin_amdgcn_readlane(aj, q * 32);
          ws[q] = __builtin_amdgcn_readlane(as, q * 32);
        }
      }
    }
    pj = pjn;
  }
  if (listlane)
    idx_out[(size_t)(q0 + half) * KK1 + l16] = kj;
}

// ---------------------------------------------------------------- EdgeConv 1 (unchanged)
__global__ __launch_bounds__(256) void edgeconv1_kernel(
    const float* __restrict__ X, const int* __restrict__ knn,
    const float* __restrict__ W1, const float* __restrict__ b1,
    const float* __restrict__ W2, const float* __restrict__ b2,
    float* __restrict__ H, unsigned short* __restrict__ Hhi,
    unsigned short* __restrict__ Hlo, float* __restrict__ SQ2) {
  __shared__ float h1[8][KK1][HIDC];
  __shared__ float xjs[8][KK1][3];
  __shared__ float xis[8][3];
  const int tid  = threadIdx.x;
  const int lane = tid & 63;
  const int wv   = __builtin_amdgcn_readfirstlane(tid >> 6);
  const int half = lane >> 5;
  const int hl   = lane & 31;
  const int lp   = wv * 2 + half;
  const int p    = blockIdx.x * 8 + lp;
  const int ch0  = hl * 4;

  if (hl < KK1) {
    int j = knn[p * KK1 + hl];
    xjs[lp][hl][0] = X[3 * j]; xjs[lp][hl][1] = X[3 * j + 1]; xjs[lp][hl][2] = X[3 * j + 2];
  } else if (hl < KK1 + 3) {
    xis[lp][hl - KK1] = X[3 * p + hl - KK1];
  }
  __syncthreads();

  f32x4 w1r[6];
  #pragma unroll
  for (int c = 0; c < 6; ++c) w1r[c] = *(const f32x4*)&W1[c * HIDC + ch0];
  f32x4 b1v = *(const f32x4*)&b1[ch0];
  const float xi0 = xis[lp][0], xi1 = xis[lp][1], xi2 = xis[lp][2];
  f32x4 base;
  #pragma unroll
  for (int c = 0; c < 4; ++c)
    base[c] = b1v[c] + xi0 * w1r[0][c] + xi1 * w1r[1][c] + xi2 * w1r[2][c];
  #pragma unroll
  for (int e = 0; e < KK1; ++e) {
    float dx = xjs[lp][e][0] - xi0, dy = xjs[lp][e][1] - xi1, dz = xjs[lp][e][2] - xi2;
    f32x4 v;
    #pragma unroll
    for (int c = 0; c < 4; ++c)
      v[c] = fmaxf(base[c] + dx * w1r[3][c] + dy * w1r[4][c] + dz * w1r[5][c], 0.f);
    *(f32x4*)&h1[lp][e][ch0] = v;
  }
  __syncthreads();

  float acc[KK1][4];
  #pragma unroll
  for (int e = 0; e < KK1; ++e)
    #pragma unroll
    for (int c = 0; c < 4; ++c) acc[e][c] = 0.f;
  for (int c4 = 0; c4 < HIDC / 4; ++c4) {
    f32x4 w2r[4];
    #pragma unroll
    for (int cc = 0; cc < 4; ++cc)
      w2r[cc] = *(const f32x4*)&W2[(c4 * 4 + cc) * HIDC + ch0];
    #pragma unroll
    for (int e = 0; e < KK1; ++e) {
      f32x4 hv = *(const f32x4*)&h1[lp][e][c4 * 4];
      #pragma unroll
      for (int cc = 0; cc < 4; ++cc)
        #pragma unroll
        for (int c = 0; c < 4; ++c) acc[e][c] += hv[cc] * w2r[cc][c];
    }
  }
  f32x4 b2v = *(const f32x4*)&b2[ch0];
  f32x4 outv;
  #pragma unroll
  for (int c = 0; c < 4; ++c) {
    float m = -INFINITY;
    #pragma unroll
    for (int e = 0; e < KK1; ++e) m = fmaxf(m, acc[e][c]);
    outv[c] = m + b2v[c];
  }
  *(f32x4*)&H[(size_t)p * HIDC + ch0] = outv;

  unsigned short hb[4], lb[4];
  #pragma unroll
  for (int c = 0; c < 4; ++c) {
    hb[c] = bf16_rn(outv[c]);
    float fh = __uint_as_float(((unsigned int)hb[c]) << 16);
    lb[c] = bf16_rn(outv[c] - fh);
  }
  *(ushort4*)&Hhi[(size_t)p * HIDC + ch0] = make_ushort4(hb[0], hb[1], hb[2], hb[3]);
  *(ushort4*)&Hlo[(size_t)p * HIDC + ch0] = make_ushort4(lb[0], lb[1], lb[2], lb[3]);

  float s = outv[0]*outv[0] + outv[1]*outv[1] + outv[2]*outv[2] + outv[3]*outv[3];
  #pragma unroll
  for (int m = 1; m <= 16; m <<= 1) s += __shfl_xor(s, m, 64);
  if (hl == 0) SQ2[p] = s;
}

// ---------------------------------------------------------------- PQ = H @ Wc (+b1 on P half)
__global__ __launch_bounds__(256) void gemm_pq_kernel(
    const float* __restrict__ H, const float* __restrict__ Wc,
    const float* __restrict__ b1, float* __restrict__ PQ) {
  __shared__ float Hs[32][HIDC];
  const int tid = threadIdx.x;
  const int rb  = blockIdx.x >> 3;
  const int cb  = blockIdx.x & 7;
  const int col = cb * 64 + (tid & 63);
  const int rg  = tid >> 6;

  #pragma unroll
  for (int u = 0; u < 4; ++u) {
    int idx = u * 256 + tid;
    int r = idx >> 5, k4 = idx & 31;
    *(f32x4*)&Hs[r][k4 * 4] = *(const f32x4*)&H[(size_t)(rb * 32 + r) * HIDC + k4 * 4];
  }
  __syncthreads();

  float acc[8] = {};
  for (int k = 0; k < HIDC; ++k) {
    float w = Wc[(size_t)k * PQC + col];
    #pragma unroll
    for (int i = 0; i < 8; ++i) acc[i] += Hs[rg * 8 + i][k] * w;
  }
  const float bb = (col < OUTC2) ? b1[col] : 0.f;
  #pragma unroll
  for (int i = 0; i < 8; ++i)
    PQ[(size_t)(rb * 32 + rg * 8 + i) * PQC + col] = acc[i] + bb;
}

// ---------------------------------------------------------------- KNN2 filter: MFMA -> LDS D -> ballot top-16
// 512 blocks x 512 thr (8 waves). Block owns 16 queries, scans all 8192 j in
// 512-row chunks. Phase A: wave w computes 4 tiles (64 j x 16 q) -> D in LDS.
// Phase B: wave w runs distributed ballot top-16 for queries {2w, 2w+1}
// (slots = lanes 0-15, wave-uniform worst, recheck semantics = exact lex).
constexpr int FQB  = 16;            // queries per block
constexpr int FJC  = 512;           // j per chunk
constexpr int FNC  = NPTS / FJC;    // 16 chunks
constexpr int FM   = 16;            // candidates kept per query
constexpr int FSTR = 521;           // D row stride (floats): 521%32=9 -> <=2-way

__global__ __launch_bounds__(512) void knn128_filter_kernel(
    const unsigned short* __restrict__ Hhi, const unsigned short* __restrict__ Hlo,
    const float* __restrict__ SQ, int* __restrict__ pi2) {
  __shared__ float D[FQB * FSTR];   // 33.3 KB
  const int tid  = threadIdx.x;
  const int lane = tid & 63;
  const int wv   = __builtin_amdgcn_readfirstlane(tid >> 6);  // 0..7
  const int col  = lane & 15;
  const int kg   = lane >> 4;
  const int qb   = blockIdx.x;
  const int qg   = qb * FQB + col;

  short8 qhi[4], qlo[4];
  #pragma unroll
  for (int s = 0; s < 4; ++s) {
    const size_t o = (size_t)qg * HIDC + s * 32 + kg * 8;
    qhi[s] = *reinterpret_cast<const short8*>(Hhi + o);
    qlo[s] = *reinterpret_cast<const short8*>(Hlo + o);
  }
  const float sqq = SQ[qg];

  // distributed top-16 state for the wave's two owned queries
  float kd0 = INFINITY, kd1 = INFINITY;
  int   kj0 = 0x7fffffff, kj1 = 0x7fffffff;
  float wd0 = INFINITY, wd1 = INFINITY;
  int   wj0 = 0x7fffffff, wj1 = 0x7fffffff;
  int   ws0 = 0, ws1 = 0;

  for (int ch = 0; ch < FNC; ++ch) {
    const int j0 = ch * FJC;
    // ---- phase A: MFMA distances -> LDS
    #pragma unroll
    for (int t = 0; t < 4; ++t) {
      const int jloc = (wv * 4 + t) * 16;
      const int jb   = j0 + jloc;
      const int arow = jb + col;
      short8 ahi[4], alo[4];
      #pragma unroll
      for (int s = 0; s < 4; ++s) {
        const size_t oa = (size_t)arow * HIDC + s * 32 + kg * 8;
        ahi[s] = *reinterpret_cast<const short8*>(Hhi + oa);
        alo[s] = *reinterpret_cast<const short8*>(Hlo + oa);
      }
      f32x4 sqjv = *reinterpret_cast<const f32x4*>(SQ + jb + kg * 4);
      f32x4 acc = {0.f, 0.f, 0.f, 0.f};
      #pragma unroll
      for (int s = 0; s < 4; ++s) {
        acc = mfma16(ahi[s], qhi[s], acc);
        acc = mfma16(ahi[s], qlo[s], acc);
        acc = mfma16(alo[s], qhi[s], acc);
      }
      // D: col = lane&15 (query), row = kg*4+r (j)  [m89/m91-validated]
      f32x4 dvv;
      #pragma unroll
      for (int r = 0; r < 4; ++r) {
        const int jgl = jb + kg * 4 + r;
        float d = sqq + sqjv[r] - 2.f * acc[r];
        dvv[r] = (jgl == qg) ? INFINITY : d;
      }
      *(f32x4*)&D[col * FSTR + jloc + kg * 4] = dvv;
    }
    __syncthreads();

    // ---- phase B: ballot top-16 for two owned queries
    auto scan_q = [&](int ql, float& kd, int& kj, float& wd, int& wj, int& ws) {
      #pragma unroll
      for (int s = 0; s < FJC / 64; ++s) {
        const float d  = D[ql * FSTR + s * 64 + lane];
        const int   jg = j0 + s * 64 + lane;
        bool c = (d < wd) || (d == wd && jg < wj);
        unsigned long long vote = __ballot(c);
        while (vote) {
          const int l = (int)__ffsll(vote) - 1;
          vote &= vote - 1;
          const float dv = rdlane_f(d, l);
          const int   jv = j0 + s * 64 + l;
          if ((dv < wd) || (dv == wd && jv < wj)) {   // recheck vs CURRENT worst
            const bool mine = (lane == ws);           // slots live in lanes 0-15
            kd = mine ? dv : kd;
            kj = mine ? jv : kj;
            float av = kd; int aj = kj; int as = col;
            #pragma unroll
            for (int m = 1; m <= 8; m <<= 1) {
              float ov = __shfl_xor(av, m, 64);
              int   oj = __shfl_xor(aj, m, 64);
              int   os = __shfl_xor(as, m, 64);
              bool g = (ov > av) || (ov == av && oj > aj);
              av = g ? ov : av; aj = g ? oj : aj; as = g ? os : as;
            }
            wd = rdlane_f(av, 0);
            wj = __builtin_amdgcn_readlane(aj, 0);
            ws = __builtin_amdgcn_readlane(as, 0);
          }
        }
      }
    };
    scan_q(wv * 2 + 0, kd0, kj0, wd0, wj0, ws0);
    scan_q(wv * 2 + 1, kd1, kj1, wd1, wj1, ws1);
    __syncthreads();
  }

  if (lane < 16) {
    pi2[(size_t)(qb * FQB + wv * 2 + 0) * FM + lane] = kj0;
    pi2[(size_t)(qb * FQB + wv * 2 + 1) * FM + lane] = kj1;
  }
}

// ---------------------------------------------------------------- exact fp32 rescore (16 cands, 16 lanes/query)
__global__ __launch_bounds__(256) void knn_rescore_kernel(
    const float* __restrict__ H, const float* __restrict__ SQ,
    const int* __restrict__ pi2, int* __restrict__ idx_out) {
  __shared__ float qrow[16][HIDC + 4];
  const int tid  = threadIdx.x;
  const int qloc = tid >> 4;        // 0..15
  const int cl   = tid & 15;        // candidate slot
  const int q0   = blockIdx.x * 16;
  const int q    = q0 + qloc;
  for (int u = tid; u < 16 * HIDC; u += 256)
    qrow[u >> 7][u & 127] = H[(size_t)(q0 + (u >> 7)) * HIDC + (u & 127)];
  __syncthreads();

  const int ci = pi2[(size_t)q * FM + cl];
  const float* crow = H + (size_t)ci * HIDC;
  float dot = 0.f;
  #pragma unroll 8
  for (int c4 = 0; c4 < HIDC / 4; ++c4) {
    f32x4 qv = *(const f32x4*)&qrow[qloc][c4 * 4];
    f32x4 cv = *(const f32x4*)(crow + c4 * 4);
    dot += qv[0] * cv[0] + qv[1] * cv[1] + qv[2] * cv[2] + qv[3] * cv[3];
  }
  float d = SQ[q] + SQ[ci] - 2.f * dot;

  float kf[KK2]; int ki[KK2];
  kf[0] = d; ki[0] = ci;
  #pragma unroll
  for (int k = 1; k < KK2; ++k) { kf[k] = INFINITY; ki[k] = 0x7fffffff; }
  #pragma unroll
  for (int dlt = 1; dlt <= 8; dlt <<= 1) {    // merge within the 16-lane group
    float of[KK2]; int oi[KK2];
    #pragma unroll
    for (int k = 0; k < KK2; ++k) { of[k] = __shfl_xor(kf[k], dlt, 64); oi[k] = __shfl_xor(ki[k], dlt, 64); }
    #pragma unroll
    for (int k = 0; k < KK2; ++k) ins_lex<KK2>(kf, ki, of[k], oi[k]);
  }
  if (cl == 0) {
    #pragma unroll
    for (int k = 0; k < KK2; ++k) idx_out[(size_t)q * KK2 + k] = ki[k];
  }
}

// ---------------------------------------------------------------- EdgeConv 2 (unchanged)
__global__ __launch_bounds__(256) void edgeconv2_kernel(
    const float* __restrict__ PQ, const int* __restrict__ knn,
    const float* __restrict__ W2, const float* __restrict__ b2,
    float* __restrict__ Out) {
  __shared__ float g1[4][KK2][OUTC2];
  __shared__ float w2s[2][8][OUTC2];
  const int tid  = threadIdx.x;
  const int lane = tid & 63;
  const int wv   = __builtin_amdgcn_readfirstlane(tid >> 6);
  const int p    = blockIdx.x * 4 + wv;
  const int ch0  = lane * 4;

  f32x4 pv = *(const f32x4*)&PQ[(size_t)p * PQC + ch0];
  #pragma unroll
  for (int e = 0; e < KK2; ++e) {
    int j = knn[p * KK2 + e];
    f32x4 qv = *(const f32x4*)&PQ[(size_t)j * PQC + OUTC2 + ch0];
    f32x4 g;
    #pragma unroll
    for (int c = 0; c < 4; ++c) g[c] = fmaxf(pv[c] + qv[c], 0.f);
    *(f32x4*)&g1[wv][e][ch0] = g;
  }

  {
    int r = tid >> 5, c0 = (tid & 31) * 8;
    *(f32x4*)&w2s[0][r][c0]     = *(const f32x4*)&W2[(size_t)r * OUTC2 + c0];
    *(f32x4*)&w2s[0][r][c0 + 4] = *(const f32x4*)&W2[(size_t)r * OUTC2 + c0 + 4];
  }
  __syncthreads();

  float acc2[KK2][4];
  #pragma unroll
  for (int e = 0; e < KK2; ++e)
    #pragma unroll
    for (int c = 0; c < 4; ++c) acc2[e][c] = 0.f;

  for (int c8 = 0; c8 < OUTC2 / 8; ++c8) {
    const int cur = c8 & 1;
    if (c8 + 1 < OUTC2 / 8) {
      int r = tid >> 5, c0 = (tid & 31) * 8;
      int gr = (c8 + 1) * 8 + r;
      *(f32x4*)&w2s[cur ^ 1][r][c0]     = *(const f32x4*)&W2[(size_t)gr * OUTC2 + c0];
      *(f32x4*)&w2s[cur ^ 1][r][c0 + 4] = *(const f32x4*)&W2[(size_t)gr * OUTC2 + c0 + 4];
    }
    f32x4 wreg[8];
    #pragma unroll
    for (int cc = 0; cc < 8; ++cc) wreg[cc] = *(const f32x4*)&w2s[cur][cc][ch0];
    #pragma unroll
    for (int e = 0; e < KK2; ++e) {
      f32x4 gv0 = *(const f32x4*)&g1[wv][e][c8 * 8];
      f32x4 gv1 = *(const f32x4*)&g1[wv][e][c8 * 8 + 4];
      #pragma unroll
      for (int cc = 0; cc < 4; ++cc)
        #pragma unroll
        for (int c = 0; c < 4; ++c) acc2[e][c] += gv0[cc] * wreg[cc][c];
      #pragma unroll
      for (int cc = 0; cc < 4; ++cc)
        #pragma unroll
        for (int c = 0; c < 4; ++c) acc2[e][c] += gv1[cc] * wreg[4 + cc][c];
    }
    __syncthreads();
  }

  f32x4 b2v = *(const f32x4*)&b2[ch0];
  f32x4 outv;
  #pragma unroll
  for (int c = 0; c < 4; ++c) {
    float m = -INFINITY;
    #pragma unroll
    for (int e = 0; e < KK2; ++e) m = fmaxf(m, acc2[e][c]);
    outv[c] = m + b2v[c];
  }
  *(f32x4*)&Out[(size_t)p * OUTC2 + ch0] = outv;
}

// ---------------------------------------------------------------- launch
extern "C" void kernel_launch(void* const* d_in, const int* in_sizes, int n_in,
                              void* d_out, int out_size, void* d_ws, size_t ws_size,
                              hipStream_t stream) {
  const float* x   = (const float*)d_in[0];
  const float* W1a = (const float*)d_in[1];
  const float* b1a = (const float*)d_in[2];
  const float* W1b = (const float*)d_in[3];
  const float* b1b = (const float*)d_in[4];
  const float* W2a = (const float*)d_in[5];
  const float* b2a = (const float*)d_in[6];
  const float* W2b = (const float*)d_in[7];
  const float* b2b = (const float*)d_in[8];
  float* out = (float*)d_out;

  float* h    = (float*)d_ws;                       // 4 MB
  float* sq2  = h + (size_t)NPTS * HIDC;
  int*   idx1 = (int*)(sq2 + NPTS);
  int*   idx2 = idx1 + (size_t)NPTS * KK1;
  unsigned short* Hhi = (unsigned short*)(idx2 + (size_t)NPTS * KK2);  // 2 MB
  unsigned short* Hlo = Hhi + (size_t)NPTS * HIDC;                     // 2 MB
  int*   pi2  = (int*)(Hlo + (size_t)NPTS * HIDC);  // 8192*16*4 = 512 KB
  float* Wc   = (float*)(pi2 + (size_t)NPTS * FM);  // 256 KB
  float* PQ   = Wc + (size_t)HIDC * PQC;            // 16 MB
  // x4 aliases h's first 128KB: knn3 finishes before edgeconv1 writes h.
  float4* x4 = (float4*)h;

  pack_x_kernel<<<(NPTS + 255) / 256, 256, 0, stream>>>(x, x4);
  prep_w1_kernel<<<(HIDC * PQC) / 256, 256, 0, stream>>>(W2a, Wc);
  knn3_kernel<<<NPTS / 8, 256, 0, stream>>>(x4, idx1);
  edgeconv1_kernel<<<NPTS / 8, 256, 0, stream>>>(x, idx1, W1a, b1a, W1b, b1b,
                                                 h, Hhi, Hlo, sq2);
  gemm_pq_kernel<<<(NPTS / 32) * 8, 256, 0, stream>>>(h, Wc, b2a, PQ);
  knn128_filter_kernel<<<NPTS / FQB, 512, 0, stream>>>(Hhi, Hlo, sq2, pi2);
  knn_rescore_kernel<<<NPTS / 16, 256, 0, stream>>>(h, sq2, pi2, idx2);
  edgeconv2_kernel<<<NPTS / 4, 256, 0, stream>>>(PQ, idx2, W2b, b2b, out);
}

// Round 9
// 724.263 us; speedup vs baseline: 1.0910x; 1.0910x over previous
//
#include <hip/hip_runtime.h>
#include <math.h>

constexpr int NPTS  = 8192;
constexpr int HIDC  = 128;
constexpr int OUTC2 = 256;
constexpr int PQC   = 512;
constexpr int KK1   = 16;
constexpr int KK2   = 8;

typedef __attribute__((ext_vector_type(8))) short short8;
typedef __attribute__((ext_vector_type(4))) float f32x4;

__device__ __forceinline__ f32x4 mfma16(short8 a, short8 b, f32x4 c) {
  return __builtin_amdgcn_mfma_f32_16x16x32_bf16(a, b, c, 0, 0, 0);
}

// packed-key insert: keys unique (j embedded) -> strict < is exact lex.
// chain = v_min_u32/v_max_u32 pairs, 2 ops per position.
template <int K>
__device__ __forceinline__ void ins_u(unsigned (&kk)[K], unsigned v) {
  if (v < kk[K - 1]) {
    kk[K - 1] = v;
    #pragma unroll
    for (int p = K - 1; p > 0; --p) {
      unsigned a = kk[p - 1], b = kk[p];
      kk[p - 1] = a < b ? a : b;
      kk[p]     = a < b ? b : a;
    }
  }
}

// lexicographic (d, idx) insert — exact fp32 merging.
template <int K>
__device__ __forceinline__ void ins_lex(float (&kf)[K], int (&ki)[K], float v, int j) {
  bool ins = (v < kf[K - 1]) || (v == kf[K - 1] && j < ki[K - 1]);
  if (ins) {
    kf[K - 1] = v; ki[K - 1] = j;
    #pragma unroll
    for (int p = K - 1; p > 0; --p) {
      float fa = kf[p - 1], fb = kf[p];
      int   ia = ki[p - 1], ib = ki[p];
      bool sw = (fb < fa) || (fb == fa && ib < ia);
      kf[p - 1] = sw ? fb : fa; ki[p - 1] = sw ? ib : ia;
      kf[p]     = sw ? fa : fb; ki[p]     = sw ? ia : ib;
    }
  }
}

__device__ __forceinline__ unsigned short bf16_rn(float x) {
  unsigned int u = __float_as_uint(x);
  unsigned int r = u + 0x7fffu + ((u >> 16) & 1u);
  return (unsigned short)(r >> 16);
}

__device__ __forceinline__ float rdlane_f(float v, int l) {
  return __int_as_float(__builtin_amdgcn_readlane(__float_as_int(v), l));
}

// ---------------------------------------------------------------- pack x
__global__ void pack_x_kernel(const float* __restrict__ x, float4* __restrict__ x4) {
  int i = blockIdx.x * blockDim.x + threadIdx.x;
  if (i < NPTS) {
    float a = x[3 * i], b = x[3 * i + 1], c = x[3 * i + 2];
    x4[i] = make_float4(a, b, c, a * a + b * b + c * c);
  }
}

// ---------------------------------------------------------------- Wc = [Wl-Wh | Wh] for layer2 stage1
__global__ void prep_w1_kernel(const float* __restrict__ W1, float* __restrict__ Wc) {
  int idx = blockIdx.x * 256 + threadIdx.x;    // 128*512
  int k = idx >> 9, c = idx & 511;
  float wh = W1[(size_t)(HIDC + k) * OUTC2 + (c & 255)];
  Wc[idx] = (c < OUTC2) ? (W1[(size_t)k * OUTC2 + c] - wh) : wh;
}

// ---------------------------------------------------------------- KNN1 (C=3, K=16), ballot-scan (R6-validated)
__global__ __launch_bounds__(256) void knn3_kernel(const float4* __restrict__ X4,
                                                   int* __restrict__ idx_out) {
  const int tid  = threadIdx.x;
  const int lane = tid & 63;
  const int wv   = __builtin_amdgcn_readfirstlane(tid >> 6);
  const int half = lane >> 5;           // which query of the wave
  const int l16  = lane & 15;           // list slot
  const bool listlane = (lane & 16) == 0;
  const int q0 = (blockIdx.x * 4 + wv) * 2;

  float qx[2], qy[2], qz[2], qw[2];
  #pragma unroll
  for (int q = 0; q < 2; ++q) {
    float4 v = X4[q0 + q];
    qx[q] = v.x; qy[q] = v.y; qz[q] = v.z; qw[q] = v.w;
  }

  float kd = INFINITY; int kj = 0x7fffffff;
  float wd[2]; int wj[2], ws[2];
  #pragma unroll
  for (int q = 0; q < 2; ++q) { wd[q] = INFINITY; wj[q] = 0x7fffffff; ws[q] = 0; }

  float4 pj = X4[lane];
  for (int j0 = 0; j0 < NPTS; j0 += 64) {
    float4 pjn = pj;
    if (j0 + 64 < NPTS) pjn = X4[j0 + 64 + lane];
    const int j = j0 + lane;
    #pragma unroll
    for (int q = 0; q < 2; ++q) {
      float d = qw[q] + pj.w - 2.f * (qx[q] * pj.x + qy[q] * pj.y + qz[q] * pj.z);
      bool c = (j != q0 + q) && ((d < wd[q]) || (d == wd[q] && j < wj[q]));
      unsigned long long vote = __ballot(c);
      while (vote) {
        const int l = (int)__ffsll(vote) - 1;
        vote &= vote - 1;
        const float dv = rdlane_f(d, l);
        const int   jv = j0 + l;
        if ((dv < wd[q]) || (dv == wd[q] && jv < wj[q])) {   // recheck vs CURRENT worst
          const bool mine = (half == q) && listlane && (l16 == ws[q]);
          kd = mine ? dv : kd;
          kj = mine ? jv : kj;
          float av = kd; int aj = kj; int as = l16;
          #pragma unroll
          for (int m = 1; m <= 8; m <<= 1) {
            float ov = __shfl_xor(av, m, 64);
            int   oj = __shfl_xor(aj, m, 64);
            int   os = __shfl_xor(as, m, 64);
            bool g = (ov > av) || (ov == av && oj > aj);
            av = g ? ov : av; aj = g ? oj : aj; as = g ? os : as;
          }
          wd[q] = rdlane_f(av, q * 32);
          wj[q] = __builtin_amdgcn_readlane(aj, q * 32);
          ws[q] = __builtin_amdgcn_readlane(as, q * 32);
        }
      }
    }
    pj = pjn;
  }
  if (listlane)
    idx_out[(size_t)(q0 + half) * KK1 + l16] = kj;
}

// ---------------------------------------------------------------- EdgeConv 1 (unchanged)
__global__ __launch_bounds__(256) void edgeconv1_kernel(
    const float* __restrict__ X, const int* __restrict__ knn,
    const float* __restrict__ W1, const float* __restrict__ b1,
    const float* __restrict__ W2, const float* __restrict__ b2,
    float* __restrict__ H, unsigned short* __restrict__ Hhi,
    unsigned short* __restrict__ Hlo, float* __restrict__ SQ2) {
  __shared__ float h1[8][KK1][HIDC];
  __shared__ float xjs[8][KK1][3];
  __shared__ float xis[8][3];
  const int tid  = threadIdx.x;
  const int lane = tid & 63;
  const int wv   = __builtin_amdgcn_readfirstlane(tid >> 6);
  const int half = lane >> 5;
  const int hl   = lane & 31;
  const int lp   = wv * 2 + half;
  const int p    = blockIdx.x * 8 + lp;
  const int ch0  = hl * 4;

  if (hl < KK1) {
    int j = knn[p * KK1 + hl];
    xjs[lp][hl][0] = X[3 * j]; xjs[lp][hl][1] = X[3 * j + 1]; xjs[lp][hl][2] = X[3 * j + 2];
  } else if (hl < KK1 + 3) {
    xis[lp][hl - KK1] = X[3 * p + hl - KK1];
  }
  __syncthreads();

  f32x4 w1r[6];
  #pragma unroll
  for (int c = 0; c < 6; ++c) w1r[c] = *(const f32x4*)&W1[c * HIDC + ch0];
  f32x4 b1v = *(const f32x4*)&b1[ch0];
  const float xi0 = xis[lp][0], xi1 = xis[lp][1], xi2 = xis[lp][2];
  f32x4 base;
  #pragma unroll
  for (int c = 0; c < 4; ++c)
    base[c] = b1v[c] + xi0 * w1r[0][c] + xi1 * w1r[1][c] + xi2 * w1r[2][c];
  #pragma unroll
  for (int e = 0; e < KK1; ++e) {
    float dx = xjs[lp][e][0] - xi0, dy = xjs[lp][e][1] - xi1, dz = xjs[lp][e][2] - xi2;
    f32x4 v;
    #pragma unroll
    for (int c = 0; c < 4; ++c)
      v[c] = fmaxf(base[c] + dx * w1r[3][c] + dy * w1r[4][c] + dz * w1r[5][c], 0.f);
    *(f32x4*)&h1[lp][e][ch0] = v;
  }
  __syncthreads();

  float acc[KK1][4];
  #pragma unroll
  for (int e = 0; e < KK1; ++e)
    #pragma unroll
    for (int c = 0; c < 4; ++c) acc[e][c] = 0.f;
  for (int c4 = 0; c4 < HIDC / 4; ++c4) {
    f32x4 w2r[4];
    #pragma unroll
    for (int cc = 0; cc < 4; ++cc)
      w2r[cc] = *(const f32x4*)&W2[(c4 * 4 + cc) * HIDC + ch0];
    #pragma unroll
    for (int e = 0; e < KK1; ++e) {
      f32x4 hv = *(const f32x4*)&h1[lp][e][c4 * 4];
      #pragma unroll
      for (int cc = 0; cc < 4; ++cc)
        #pragma unroll
        for (int c = 0; c < 4; ++c) acc[e][c] += hv[cc] * w2r[cc][c];
    }
  }
  f32x4 b2v = *(const f32x4*)&b2[ch0];
  f32x4 outv;
  #pragma unroll
  for (int c = 0; c < 4; ++c) {
    float m = -INFINITY;
    #pragma unroll
    for (int e = 0; e < KK1; ++e) m = fmaxf(m, acc[e][c]);
    outv[c] = m + b2v[c];
  }
  *(f32x4*)&H[(size_t)p * HIDC + ch0] = outv;

  unsigned short hb[4], lb[4];
  #pragma unroll
  for (int c = 0; c < 4; ++c) {
    hb[c] = bf16_rn(outv[c]);
    float fh = __uint_as_float(((unsigned int)hb[c]) << 16);
    lb[c] = bf16_rn(outv[c] - fh);
  }
  *(ushort4*)&Hhi[(size_t)p * HIDC + ch0] = make_ushort4(hb[0], hb[1], hb[2], hb[3]);
  *(ushort4*)&Hlo[(size_t)p * HIDC + ch0] = make_ushort4(lb[0], lb[1], lb[2], lb[3]);

  float s = outv[0]*outv[0] + outv[1]*outv[1] + outv[2]*outv[2] + outv[3]*outv[3];
  #pragma unroll
  for (int m = 1; m <= 16; m <<= 1) s += __shfl_xor(s, m, 64);
  if (hl == 0) SQ2[p] = s;
}

// ---------------------------------------------------------------- PQ = H @ Wc (+b1 on P half)
__global__ __launch_bounds__(256) void gemm_pq_kernel(
    const float* __restrict__ H, const float* __restrict__ Wc,
    const float* __restrict__ b1, float* __restrict__ PQ) {
  __shared__ float Hs[32][HIDC];
  const int tid = threadIdx.x;
  const int rb  = blockIdx.x >> 3;
  const int cb  = blockIdx.x & 7;
  const int col = cb * 64 + (tid & 63);
  const int rg  = tid >> 6;

  #pragma unroll
  for (int u = 0; u < 4; ++u) {
    int idx = u * 256 + tid;
    int r = idx >> 5, k4 = idx & 31;
    *(f32x4*)&Hs[r][k4 * 4] = *(const f32x4*)&H[(size_t)(rb * 32 + r) * HIDC + k4 * 4];
  }
  __syncthreads();

  float acc[8] = {};
  for (int k = 0; k < HIDC; ++k) {
    float w = Wc[(size_t)k * PQC + col];
    #pragma unroll
    for (int i = 0; i < 8; ++i) acc[i] += Hs[rg * 8 + i][k] * w;
  }
  const float bb = (col < OUTC2) ? b1[col] : 0.f;
  #pragma unroll
  for (int i = 0; i < 8; ++i)
    PQ[(size_t)(rb * 32 + rg * 8 + i) * PQC + col] = acc[i] + bb;
}

// ---------------------------------------------------------------- KNN2 filter (MFMA bf16x2, 3 terms)
// R7 structure + packed u32 keys + JSPLIT=16 (8192 waves -> 8/SIMD).
// key = (bits(max(d,0)) & 0xFFFFE000) | j  (NPTS=2^13) -> strict-< = exact
// lex on (d_trunc10, j). Per-lane top-8 of its 128-cand stream, ^16/^32
// kg-merge -> exact top-8 per (query, split). 128 cands/query to rescore.
constexpr int JSPLIT = 16;
constexpr int JPB2   = NPTS / JSPLIT;   // 512 rows per split
constexpr int NT2    = JPB2 / 16;       // 32 tiles
constexpr int CPQ    = JSPLIT * KK2;    // 128 candidates per query

__global__ __launch_bounds__(256) void knn128_filter_kernel(
    const unsigned short* __restrict__ Hhi, const unsigned short* __restrict__ Hlo,
    const float* __restrict__ SQ, int* __restrict__ pi2) {
  const int tid  = threadIdx.x;
  const int lane = tid & 63;
  const int wv   = __builtin_amdgcn_readfirstlane(tid >> 6);
  const int qb   = blockIdx.x >> 4;     // 128 query-blocks of 64
  const int js   = blockIdx.x & 15;
  const int col  = lane & 15;
  const int kg   = lane >> 4;
  const int qg   = qb * 64 + wv * 16 + col;

  short8 qhi[4], qlo[4];
  #pragma unroll
  for (int s = 0; s < 4; ++s) {
    const size_t o = (size_t)qg * HIDC + s * 32 + kg * 8;
    qhi[s] = *reinterpret_cast<const short8*>(Hhi + o);
    qlo[s] = *reinterpret_cast<const short8*>(Hlo + o);
  }
  const float sqq = SQ[qg];

  unsigned kk[KK2];
  #pragma unroll
  for (int k = 0; k < KK2; ++k) kk[k] = 0xFFFFFFFFu;

  const int jbase = js * JPB2;
  for (int it = 0; it < NT2; ++it) {
    const int jb = jbase + it * 16;
    const int arow = jb + col;
    short8 ahi[4], alo[4];
    #pragma unroll
    for (int s = 0; s < 4; ++s) {
      const size_t oa = (size_t)arow * HIDC + s * 32 + kg * 8;
      ahi[s] = *reinterpret_cast<const short8*>(Hhi + oa);
      alo[s] = *reinterpret_cast<const short8*>(Hlo + oa);
    }
    f32x4 sqjv = *reinterpret_cast<const f32x4*>(SQ + jb + kg * 4);

    f32x4 acc = {0.f, 0.f, 0.f, 0.f};
    #pragma unroll
    for (int s = 0; s < 4; ++s) {
      acc = mfma16(ahi[s], qhi[s], acc);
      acc = mfma16(ahi[s], qlo[s], acc);
      acc = mfma16(alo[s], qhi[s], acc);
    }
    // D: col = lane&15 (query), row = kg*4+r (j)  [m89/m91-validated]
    #pragma unroll
    for (int r = 0; r < 4; ++r) {
      const int jg = jb + kg * 4 + r;
      float d = fmaxf(sqq + sqjv[r] - 2.f * acc[r], 0.f);
      unsigned key = (__float_as_uint(d) & 0xFFFFE000u) | (unsigned)jg;
      if (jg == qg) key = 0xFFFFFFFFu;
      ins_u<KK2>(kk, key);
    }
  }

  // merge 4 kgroup lists (same query at lanes ^16, ^32) -> top-8 of split
  #pragma unroll
  for (int dlt = 16; dlt <= 32; dlt <<= 1) {
    unsigned ok[KK2];
    #pragma unroll
    for (int k = 0; k < KK2; ++k) ok[k] = __shfl_xor((int)kk[k], dlt, 64);
    #pragma unroll
    for (int k = 0; k < KK2; ++k) ins_u<KK2>(kk, ok[k]);
  }
  if (lane < 16) {
    const size_t base = (size_t)qg * CPQ + js * KK2;
    #pragma unroll
    for (int k = 0; k < KK2; ++k) pi2[base + k] = (int)(kk[k] & 0x1FFFu);
  }
}

// ---------------------------------------------------------------- exact fp32 rescore (128 cands, 2/lane sequential)
__global__ __launch_bounds__(256) void knn_rescore_kernel(
    const float* __restrict__ H, const float* __restrict__ SQ,
    const int* __restrict__ pi2, int* __restrict__ idx_out) {
  __shared__ float qrow[4][HIDC];
  const int tid  = threadIdx.x;
  const int wv   = tid >> 6;
  const int lane = tid & 63;
  const int q0   = blockIdx.x * 4;
  const int q    = q0 + wv;
  for (int u = tid; u < 4 * HIDC; u += 256)
    qrow[u >> 7][u & 127] = H[(size_t)(q0 + (u >> 7)) * HIDC + (u & 127)];
  __syncthreads();

  const int c0 = pi2[(size_t)q * CPQ + lane];
  const int c1 = pi2[(size_t)q * CPQ + 64 + lane];
  const float sqq = SQ[q];

  float dot0 = 0.f;
  {
    const float* crow = H + (size_t)c0 * HIDC;
    #pragma unroll 8
    for (int c4 = 0; c4 < HIDC / 4; ++c4) {
      f32x4 qv = *(const f32x4*)&qrow[wv][c4 * 4];
      f32x4 cv = *(const f32x4*)(crow + c4 * 4);
      dot0 += qv[0] * cv[0] + qv[1] * cv[1] + qv[2] * cv[2] + qv[3] * cv[3];
    }
  }
  float d0 = sqq + SQ[c0] - 2.f * dot0;

  float dot1 = 0.f;
  {
    const float* crow = H + (size_t)c1 * HIDC;
    #pragma unroll 8
    for (int c4 = 0; c4 < HIDC / 4; ++c4) {
      f32x4 qv = *(const f32x4*)&qrow[wv][c4 * 4];
      f32x4 cv = *(const f32x4*)(crow + c4 * 4);
      dot1 += qv[0] * cv[0] + qv[1] * cv[1] + qv[2] * cv[2] + qv[3] * cv[3];
    }
  }
  float d1 = sqq + SQ[c1] - 2.f * dot1;

  float kf[KK2]; int ki[KK2];
  kf[0] = d0; ki[0] = c0;
  #pragma unroll
  for (int k = 1; k < KK2; ++k) { kf[k] = INFINITY; ki[k] = 0x7fffffff; }
  ins_lex<KK2>(kf, ki, d1, c1);
  #pragma unroll
  for (int dlt = 1; dlt <= 32; dlt <<= 1) {
    float of[KK2]; int oi[KK2];
    #pragma unroll
    for (int k = 0; k < KK2; ++k) { of[k] = __shfl_xor(kf[k], dlt, 64); oi[k] = __shfl_xor(ki[k], dlt, 64); }
    #pragma unroll
    for (int k = 0; k < KK2; ++k) ins_lex<KK2>(kf, ki, of[k], oi[k]);
  }
  if (lane == 0) {
    #pragma unroll
    for (int k = 0; k < KK2; ++k) idx_out[(size_t)q * KK2 + k] = ki[k];
  }
}

// ---------------------------------------------------------------- EdgeConv 2 (unchanged)
__global__ __launch_bounds__(256) void edgeconv2_kernel(
    const float* __restrict__ PQ, const int* __restrict__ knn,
    const float* __restrict__ W2, const float* __restrict__ b2,
    float* __restrict__ Out) {
  __shared__ float g1[4][KK2][OUTC2];
  __shared__ float w2s[2][8][OUTC2];
  const int tid  = threadIdx.x;
  const int lane = tid & 63;
  const int wv   = __builtin_amdgcn_readfirstlane(tid >> 6);
  const int p    = blockIdx.x * 4 + wv;
  const int ch0  = lane * 4;

  f32x4 pv = *(const f32x4*)&PQ[(size_t)p * PQC + ch0];
  #pragma unroll
  for (int e = 0; e < KK2; ++e) {
    int j = knn[p * KK2 + e];
    f32x4 qv = *(const f32x4*)&PQ[(size_t)j * PQC + OUTC2 + ch0];
    f32x4 g;
    #pragma unroll
    for (int c = 0; c < 4; ++c) g[c] = fmaxf(pv[c] + qv[c], 0.f);
    *(f32x4*)&g1[wv][e][ch0] = g;
  }

  {
    int r = tid >> 5, c0 = (tid & 31) * 8;
    *(f32x4*)&w2s[0][r][c0]     = *(const f32x4*)&W2[(size_t)r * OUTC2 + c0];
    *(f32x4*)&w2s[0][r][c0 + 4] = *(const f32x4*)&W2[(size_t)r * OUTC2 + c0 + 4];
  }
  __syncthreads();

  float acc2[KK2][4];
  #pragma unroll
  for (int e = 0; e < KK2; ++e)
    #pragma unroll
    for (int c = 0; c < 4; ++c) acc2[e][c] = 0.f;

  for (int c8 = 0; c8 < OUTC2 / 8; ++c8) {
    const int cur = c8 & 1;
    if (c8 + 1 < OUTC2 / 8) {
      int r = tid >> 5, c0 = (tid & 31) * 8;
      int gr = (c8 + 1) * 8 + r;
      *(f32x4*)&w2s[cur ^ 1][r][c0]     = *(const f32x4*)&W2[(size_t)gr * OUTC2 + c0];
      *(f32x4*)&w2s[cur ^ 1][r][c0 + 4] = *(const f32x4*)&W2[(size_t)gr * OUTC2 + c0 + 4];
    }
    f32x4 wreg[8];
    #pragma unroll
    for (int cc = 0; cc < 8; ++cc) wreg[cc] = *(const f32x4*)&w2s[cur][cc][ch0];
    #pragma unroll
    for (int e = 0; e < KK2; ++e) {
      f32x4 gv0 = *(const f32x4*)&g1[wv][e][c8 * 8];
      f32x4 gv1 = *(const f32x4*)&g1[wv][e][c8 * 8 + 4];
      #pragma unroll
      for (int cc = 0; cc < 4; ++cc)
        #pragma unroll
        for (int c = 0; c < 4; ++c) acc2[e][c] += gv0[cc] * wreg[cc][c];
      #pragma unroll
      for (int cc = 0; cc < 4; ++cc)
        #pragma unroll
        for (int c = 0; c < 4; ++c) acc2[e][c] += gv1[cc] * wreg[4 + cc][c];
    }
    __syncthreads();
  }

  f32x4 b2v = *(const f32x4*)&b2[ch0];
  f32x4 outv;
  #pragma unroll
  for (int c = 0; c < 4; ++c) {
    float m = -INFINITY;
    #pragma unroll
    for (int e = 0; e < KK2; ++e) m = fmaxf(m, acc2[e][c]);
    outv[c] = m + b2v[c];
  }
  *(f32x4*)&Out[(size_t)p * OUTC2 + ch0] = outv;
}

// ---------------------------------------------------------------- launch
extern "C" void kernel_launch(void* const* d_in, const int* in_sizes, int n_in,
                              void* d_out, int out_size, void* d_ws, size_t ws_size,
                              hipStream_t stream) {
  const float* x   = (const float*)d_in[0];
  const float* W1a = (const float*)d_in[1];
  const float* b1a = (const float*)d_in[2];
  const float* W1b = (const float*)d_in[3];
  const float* b1b = (const float*)d_in[4];
  const float* W2a = (const float*)d_in[5];
  const float* b2a = (const float*)d_in[6];
  const float* W2b = (const float*)d_in[7];
  const float* b2b = (const float*)d_in[8];
  float* out = (float*)d_out;

  float* h    = (float*)d_ws;                       // 4 MB
  float* sq2  = h + (size_t)NPTS * HIDC;
  int*   idx1 = (int*)(sq2 + NPTS);
  int*   idx2 = idx1 + (size_t)NPTS * KK1;
  unsigned short* Hhi = (unsigned short*)(idx2 + (size_t)NPTS * KK2);  // 2 MB
  unsigned short* Hlo = Hhi + (size_t)NPTS * HIDC;                     // 2 MB
  int*   pi2  = (int*)(Hlo + (size_t)NPTS * HIDC);  // 8192*128*4 = 4 MB
  float* Wc   = (float*)(pi2 + (size_t)NPTS * CPQ); // 256 KB
  float* PQ   = Wc + (size_t)HIDC * PQC;            // 16 MB
  // x4 aliases h's first 128KB: knn3 finishes before edgeconv1 writes h.
  float4* x4 = (float4*)h;

  pack_x_kernel<<<(NPTS + 255) / 256, 256, 0, stream>>>(x, x4);
  prep_w1_kernel<<<(HIDC * PQC) / 256, 256, 0, stream>>>(W2a, Wc);
  knn3_kernel<<<NPTS / 8, 256, 0, stream>>>(x4, idx1);
  edgeconv1_kernel<<<NPTS / 8, 256, 0, stream>>>(x, idx1, W1a, b1a, W1b, b1b,
                                                 h, Hhi, Hlo, sq2);
  gemm_pq_kernel<<<(NPTS / 32) * 8, 256, 0, stream>>>(h, Wc, b2a, PQ);
  knn128_filter_kernel<<<(NPTS / 64) * JSPLIT, 256, 0, stream>>>(Hhi, Hlo, sq2, pi2);
  knn_rescore_kernel<<<NPTS / 4, 256, 0, stream>>>(h, sq2, pi2, idx2);
  edgeconv2_kernel<<<NPTS / 4, 256, 0, stream>>>(PQ, idx2, W2b, b2b, out);
}

// Round 10
// 535.343 us; speedup vs baseline: 1.4760x; 1.3529x over previous
//
#include <hip/hip_runtime.h>
#include <math.h>

constexpr int NPTS  = 8192;
constexpr int HIDC  = 128;
constexpr int OUTC2 = 256;
constexpr int PQC   = 512;
constexpr int KK1   = 16;
constexpr int KK2   = 8;

typedef __attribute__((ext_vector_type(8))) short short8;
typedef __attribute__((ext_vector_type(4))) float f32x4;

__device__ __forceinline__ f32x4 mfma16(short8 a, short8 b, f32x4 c) {
  return __builtin_amdgcn_mfma_f32_16x16x32_bf16(a, b, c, 0, 0, 0);
}

__device__ __forceinline__ void async_ld16(void* lds, const void* g) {
  __builtin_amdgcn_global_load_lds(
      (const __attribute__((address_space(1))) unsigned int*)g,
      (__attribute__((address_space(3))) unsigned int*)lds, 16, 0, 0);
}

// packed-key insert: keys unique (j embedded) -> strict < is exact lex.
template <int K>
__device__ __forceinline__ void ins_u(unsigned (&kk)[K], unsigned v) {
  if (v < kk[K - 1]) {
    kk[K - 1] = v;
    #pragma unroll
    for (int p = K - 1; p > 0; --p) {
      unsigned a = kk[p - 1], b = kk[p];
      kk[p - 1] = a < b ? a : b;
      kk[p]     = a < b ? b : a;
    }
  }
}

// lexicographic (d, idx) insert — exact fp32 merging.
template <int K>
__device__ __forceinline__ void ins_lex(float (&kf)[K], int (&ki)[K], float v, int j) {
  bool ins = (v < kf[K - 1]) || (v == kf[K - 1] && j < ki[K - 1]);
  if (ins) {
    kf[K - 1] = v; ki[K - 1] = j;
    #pragma unroll
    for (int p = K - 1; p > 0; --p) {
      float fa = kf[p - 1], fb = kf[p];
      int   ia = ki[p - 1], ib = ki[p];
      bool sw = (fb < fa) || (fb == fa && ib < ia);
      kf[p - 1] = sw ? fb : fa; ki[p - 1] = sw ? ib : ia;
      kf[p]     = sw ? fa : fb; ki[p]     = sw ? ia : ib;
    }
  }
}

__device__ __forceinline__ unsigned short bf16_rn(float x) {
  unsigned int u = __float_as_uint(x);
  unsigned int r = u + 0x7fffu + ((u >> 16) & 1u);
  return (unsigned short)(r >> 16);
}

__device__ __forceinline__ float rdlane_f(float v, int l) {
  return __int_as_float(__builtin_amdgcn_readlane(__float_as_int(v), l));
}

// ---------------------------------------------------------------- pack x
__global__ void pack_x_kernel(const float* __restrict__ x, float4* __restrict__ x4) {
  int i = blockIdx.x * blockDim.x + threadIdx.x;
  if (i < NPTS) {
    float a = x[3 * i], b = x[3 * i + 1], c = x[3 * i + 2];
    x4[i] = make_float4(a, b, c, a * a + b * b + c * c);
  }
}

// ---------------------------------------------------------------- Wc = [Wl-Wh | Wh] for layer2 stage1
__global__ void prep_w1_kernel(const float* __restrict__ W1, float* __restrict__ Wc) {
  int idx = blockIdx.x * 256 + threadIdx.x;    // 128*512
  int k = idx >> 9, c = idx & 511;
  float wh = W1[(size_t)(HIDC + k) * OUTC2 + (c & 255)];
  Wc[idx] = (c < OUTC2) ? (W1[(size_t)k * OUTC2 + c] - wh) : wh;
}

// ---------------------------------------------------------------- KNN1 (C=3, K=16), ballot-scan (R6-validated)
__global__ __launch_bounds__(256) void knn3_kernel(const float4* __restrict__ X4,
                                                   int* __restrict__ idx_out) {
  const int tid  = threadIdx.x;
  const int lane = tid & 63;
  const int wv   = __builtin_amdgcn_readfirstlane(tid >> 6);
  const int half = lane >> 5;           // which query of the wave
  const int l16  = lane & 15;           // list slot
  const bool listlane = (lane & 16) == 0;
  const int q0 = (blockIdx.x * 4 + wv) * 2;

  float qx[2], qy[2], qz[2], qw[2];
  #pragma unroll
  for (int q = 0; q < 2; ++q) {
    float4 v = X4[q0 + q];
    qx[q] = v.x; qy[q] = v.y; qz[q] = v.z; qw[q] = v.w;
  }

  float kd = INFINITY; int kj = 0x7fffffff;
  float wd[2]; int wj[2], ws[2];
  #pragma unroll
  for (int q = 0; q < 2; ++q) { wd[q] = INFINITY; wj[q] = 0x7fffffff; ws[q] = 0; }

  float4 pj = X4[lane];
  for (int j0 = 0; j0 < NPTS; j0 += 64) {
    float4 pjn = pj;
    if (j0 + 64 < NPTS) pjn = X4[j0 + 64 + lane];
    const int j = j0 + lane;
    #pragma unroll
    for (int q = 0; q < 2; ++q) {
      float d = qw[q] + pj.w - 2.f * (qx[q] * pj.x + qy[q] * pj.y + qz[q] * pj.z);
      bool c = (j != q0 + q) && ((d < wd[q]) || (d == wd[q] && j < wj[q]));
      unsigned long long vote = __ballot(c);
      while (vote) {
        const int l = (int)__ffsll(vote) - 1;
        vote &= vote - 1;
        const float dv = rdlane_f(d, l);
        const int   jv = j0 + l;
        if ((dv < wd[q]) || (dv == wd[q] && jv < wj[q])) {   // recheck vs CURRENT worst
          const bool mine = (half == q) && listlane && (l16 == ws[q]);
          kd = mine ? dv : kd;
          kj = mine ? jv : kj;
          float av = kd; int aj = kj; int as = l16;
          #pragma unroll
          for (int m = 1; m <= 8; m <<= 1) {
            float ov = __shfl_xor(av, m, 64);
            int   oj = __shfl_xor(aj, m, 64);
            int   os = __shfl_xor(as, m, 64);
            bool g = (ov > av) || (ov == av && oj > aj);
            av = g ? ov : av; aj = g ? oj : aj; as = g ? os : as;
          }
          wd[q] = rdlane_f(av, q * 32);
          wj[q] = __builtin_amdgcn_readlane(aj, q * 32);
          ws[q] = __builtin_amdgcn_readlane(as, q * 32);
        }
      }
    }
    pj = pjn;
  }
  if (listlane)
    idx_out[(size_t)(q0 + half) * KK1 + l16] = kj;
}

// ---------------------------------------------------------------- EdgeConv 1 (unchanged)
__global__ __launch_bounds__(256) void edgeconv1_kernel(
    const float* __restrict__ X, const int* __restrict__ knn,
    const float* __restrict__ W1, const float* __restrict__ b1,
    const float* __restrict__ W2, const float* __restrict__ b2,
    float* __restrict__ H, unsigned short* __restrict__ Hhi,
    unsigned short* __restrict__ Hlo, float* __restrict__ SQ2) {
  __shared__ float h1[8][KK1][HIDC];
  __shared__ float xjs[8][KK1][3];
  __shared__ float xis[8][3];
  const int tid  = threadIdx.x;
  const int lane = tid & 63;
  const int wv   = __builtin_amdgcn_readfirstlane(tid >> 6);
  const int half = lane >> 5;
  const int hl   = lane & 31;
  const int lp   = wv * 2 + half;
  const int p    = blockIdx.x * 8 + lp;
  const int ch0  = hl * 4;

  if (hl < KK1) {
    int j = knn[p * KK1 + hl];
    xjs[lp][hl][0] = X[3 * j]; xjs[lp][hl][1] = X[3 * j + 1]; xjs[lp][hl][2] = X[3 * j + 2];
  } else if (hl < KK1 + 3) {
    xis[lp][hl - KK1] = X[3 * p + hl - KK1];
  }
  __syncthreads();

  f32x4 w1r[6];
  #pragma unroll
  for (int c = 0; c < 6; ++c) w1r[c] = *(const f32x4*)&W1[c * HIDC + ch0];
  f32x4 b1v = *(const f32x4*)&b1[ch0];
  const float xi0 = xis[lp][0], xi1 = xis[lp][1], xi2 = xis[lp][2];
  f32x4 base;
  #pragma unroll
  for (int c = 0; c < 4; ++c)
    base[c] = b1v[c] + xi0 * w1r[0][c] + xi1 * w1r[1][c] + xi2 * w1r[2][c];
  #pragma unroll
  for (int e = 0; e < KK1; ++e) {
    float dx = xjs[lp][e][0] - xi0, dy = xjs[lp][e][1] - xi1, dz = xjs[lp][e][2] - xi2;
    f32x4 v;
    #pragma unroll
    for (int c = 0; c < 4; ++c)
      v[c] = fmaxf(base[c] + dx * w1r[3][c] + dy * w1r[4][c] + dz * w1r[5][c], 0.f);
    *(f32x4*)&h1[lp][e][ch0] = v;
  }
  __syncthreads();

  float acc[KK1][4];
  #pragma unroll
  for (int e = 0; e < KK1; ++e)
    #pragma unroll
    for (int c = 0; c < 4; ++c) acc[e][c] = 0.f;
  for (int c4 = 0; c4 < HIDC / 4; ++c4) {
    f32x4 w2r[4];
    #pragma unroll
    for (int cc = 0; cc < 4; ++cc)
      w2r[cc] = *(const f32x4*)&W2[(c4 * 4 + cc) * HIDC + ch0];
    #pragma unroll
    for (int e = 0; e < KK1; ++e) {
      f32x4 hv = *(const f32x4*)&h1[lp][e][c4 * 4];
      #pragma unroll
      for (int cc = 0; cc < 4; ++cc)
        #pragma unroll
        for (int c = 0; c < 4; ++c) acc[e][c] += hv[cc] * w2r[cc][c];
    }
  }
  f32x4 b2v = *(const f32x4*)&b2[ch0];
  f32x4 outv;
  #pragma unroll
  for (int c = 0; c < 4; ++c) {
    float m = -INFINITY;
    #pragma unroll
    for (int e = 0; e < KK1; ++e) m = fmaxf(m, acc[e][c]);
    outv[c] = m + b2v[c];
  }
  *(f32x4*)&H[(size_t)p * HIDC + ch0] = outv;

  unsigned short hb[4], lb[4];
  #pragma unroll
  for (int c = 0; c < 4; ++c) {
    hb[c] = bf16_rn(outv[c]);
    float fh = __uint_as_float(((unsigned int)hb[c]) << 16);
    lb[c] = bf16_rn(outv[c] - fh);
  }
  *(ushort4*)&Hhi[(size_t)p * HIDC + ch0] = make_ushort4(hb[0], hb[1], hb[2], hb[3]);
  *(ushort4*)&Hlo[(size_t)p * HIDC + ch0] = make_ushort4(lb[0], lb[1], lb[2], lb[3]);

  float s = outv[0]*outv[0] + outv[1]*outv[1] + outv[2]*outv[2] + outv[3]*outv[3];
  #pragma unroll
  for (int m = 1; m <= 16; m <<= 1) s += __shfl_xor(s, m, 64);
  if (hl == 0) SQ2[p] = s;
}

// ---------------------------------------------------------------- PQ = H @ Wc (+b1 on P half)
__global__ __launch_bounds__(256) void gemm_pq_kernel(
    const float* __restrict__ H, const float* __restrict__ Wc,
    const float* __restrict__ b1, float* __restrict__ PQ) {
  __shared__ float Hs[32][HIDC];
  const int tid = threadIdx.x;
  const int rb  = blockIdx.x >> 3;
  const int cb  = blockIdx.x & 7;
  const int col = cb * 64 + (tid & 63);
  const int rg  = tid >> 6;

  #pragma unroll
  for (int u = 0; u < 4; ++u) {
    int idx = u * 256 + tid;
    int r = idx >> 5, k4 = idx & 31;
    *(f32x4*)&Hs[r][k4 * 4] = *(const f32x4*)&H[(size_t)(rb * 32 + r) * HIDC + k4 * 4];
  }
  __syncthreads();

  float acc[8] = {};
  for (int k = 0; k < HIDC; ++k) {
    float w = Wc[(size_t)k * PQC + col];
    #pragma unroll
    for (int i = 0; i < 8; ++i) acc[i] += Hs[rg * 8 + i][k] * w;
  }
  const float bb = (col < OUTC2) ? b1[col] : 0.f;
  #pragma unroll
  for (int i = 0; i < 8; ++i)
    PQ[(size_t)(rb * 32 + rg * 8 + i) * PQC + col] = acc[i] + bb;
}

// ---------------------------------------------------------------- KNN2 filter (MFMA bf16x2, LDS A-tile sharing)
// Block = 256 thr (4 waves), 64 queries x 512-j split. 16-row j-chunks
// (hi+lo = 8 KB) double-buffered in LDS via coalesced global_load_lds with
// pre-swizzled source (slot ^= row&7) so ds_read_b128 fragments are
// conflict-free. All 4 waves share each chunk (4x fewer global insts, and
// contiguous). Selection machinery identical to R9 (passed, absmax 9.8e-4).
constexpr int JSPLIT = 16;
constexpr int JPB2   = NPTS / JSPLIT;   // 512 rows per split
constexpr int NCH    = JPB2 / 16;       // 32 chunks of 16 rows
constexpr int CPQ    = JSPLIT * KK2;    // 128 candidates per query

__global__ __launch_bounds__(256) void knn128_filter_kernel(
    const unsigned short* __restrict__ Hhi, const unsigned short* __restrict__ Hlo,
    const float* __restrict__ SQ, int* __restrict__ pi2) {
  // [buf][hi/lo][16 rows * 128 ch] = 2*2*4KB = 16 KB
  __shared__ __align__(16) unsigned short As[2][2][16 * HIDC];
  const int tid  = threadIdx.x;
  const int lane = tid & 63;
  const int wv   = __builtin_amdgcn_readfirstlane(tid >> 6);
  const int qb   = blockIdx.x >> 4;     // 128 query-blocks of 64
  const int js   = blockIdx.x & 15;
  const int col  = lane & 15;
  const int kg   = lane >> 4;
  const int qg   = qb * 64 + wv * 16 + col;

  short8 qhi[4], qlo[4];
  #pragma unroll
  for (int s = 0; s < 4; ++s) {
    const size_t o = (size_t)qg * HIDC + s * 32 + kg * 8;
    qhi[s] = *reinterpret_cast<const short8*>(Hhi + o);
    qlo[s] = *reinterpret_cast<const short8*>(Hlo + o);
  }
  const float sqq = SQ[qg];

  unsigned kk[KK2];
  #pragma unroll
  for (int k = 0; k < KK2; ++k) kk[k] = 0xFFFFFFFFu;

  const int jbase = js * JPB2;

  // wave wv stages rows 4wv..4wv+3 of a chunk (1 KB hi + 1 KB lo, coalesced,
  // contiguous). Source slot pre-swizzled: LDS[row][s] = G[row][s ^ (row&7)].
  const int srow = 4 * wv + (lane >> 4);       // local row this lane covers
  const int sslt = (lane & 15) ^ (srow & 7);   // swizzled 16B slot in source
  auto stage = [&](int buf, int ch) {
    const size_t gofs = (size_t)(jbase + ch * 16 + srow) * HIDC + sslt * 8;
    async_ld16((char*)&As[buf][0][0] + wv * 1024, Hhi + gofs);
    async_ld16((char*)&As[buf][1][0] + wv * 1024, Hlo + gofs);
  };

  stage(0, 0);
  asm volatile("s_waitcnt vmcnt(0)" ::: "memory");
  __syncthreads();

  for (int ch = 0; ch < NCH; ++ch) {
    const int cur = ch & 1;
    if (ch + 1 < NCH) stage(cur ^ 1, ch + 1);

    const int jb = jbase + ch * 16;
    // fragments from LDS: row = col, logical slot = s*4+kg, swizzled ^ (col&7)
    short8 ahi[4], alo[4];
    const int rowb = col * 256;
    #pragma unroll
    for (int s = 0; s < 4; ++s) {
      const int sl = ((s * 4 + kg) ^ (col & 7)) * 16;
      ahi[s] = *(const short8*)((const char*)&As[cur][0][0] + rowb + sl);
      alo[s] = *(const short8*)((const char*)&As[cur][1][0] + rowb + sl);
    }
    f32x4 sqjv = *reinterpret_cast<const f32x4*>(SQ + jb + kg * 4);

    f32x4 acc = {0.f, 0.f, 0.f, 0.f};
    #pragma unroll
    for (int s = 0; s < 4; ++s) {
      acc = mfma16(ahi[s], qhi[s], acc);
      acc = mfma16(ahi[s], qlo[s], acc);
      acc = mfma16(alo[s], qhi[s], acc);
    }
    // D: col = lane&15 (query), row = kg*4+r (j)  [m89/m91-validated]
    #pragma unroll
    for (int r = 0; r < 4; ++r) {
      const int jg = jb + kg * 4 + r;
      float d = fmaxf(sqq + sqjv[r] - 2.f * acc[r], 0.f);
      unsigned key = (__float_as_uint(d) & 0xFFFFE000u) | (unsigned)jg;
      if (jg == qg) key = 0xFFFFFFFFu;
      ins_u<KK2>(kk, key);
    }
    asm volatile("s_waitcnt vmcnt(0)" ::: "memory");
    __syncthreads();
  }

  // merge 4 kgroup lists (same query at lanes ^16, ^32) -> top-8 of split
  #pragma unroll
  for (int dlt = 16; dlt <= 32; dlt <<= 1) {
    unsigned ok[KK2];
    #pragma unroll
    for (int k = 0; k < KK2; ++k) ok[k] = __shfl_xor((int)kk[k], dlt, 64);
    #pragma unroll
    for (int k = 0; k < KK2; ++k) ins_u<KK2>(kk, ok[k]);
  }
  if (lane < 16) {
    const size_t base = (size_t)qg * CPQ + js * KK2;
    #pragma unroll
    for (int k = 0; k < KK2; ++k) pi2[base + k] = (int)(kk[k] & 0x1FFFu);
  }
}

// ---------------------------------------------------------------- exact fp32 rescore (128 cands, 2/lane sequential)
__global__ __launch_bounds__(256) void knn_rescore_kernel(
    const float* __restrict__ H, const float* __restrict__ SQ,
    const int* __restrict__ pi2, int* __restrict__ idx_out) {
  __shared__ float qrow[4][HIDC];
  const int tid  = threadIdx.x;
  const int wv   = tid >> 6;
  const int lane = tid & 63;
  const int q0   = blockIdx.x * 4;
  const int q    = q0 + wv;
  for (int u = tid; u < 4 * HIDC; u += 256)
    qrow[u >> 7][u & 127] = H[(size_t)(q0 + (u >> 7)) * HIDC + (u & 127)];
  __syncthreads();

  const int c0 = pi2[(size_t)q * CPQ + lane];
  const int c1 = pi2[(size_t)q * CPQ + 64 + lane];
  const float sqq = SQ[q];

  float dot0 = 0.f;
  {
    const float* crow = H + (size_t)c0 * HIDC;
    #pragma unroll 8
    for (int c4 = 0; c4 < HIDC / 4; ++c4) {
      f32x4 qv = *(const f32x4*)&qrow[wv][c4 * 4];
      f32x4 cv = *(const f32x4*)(crow + c4 * 4);
      dot0 += qv[0] * cv[0] + qv[1] * cv[1] + qv[2] * cv[2] + qv[3] * cv[3];
    }
  }
  float d0 = sqq + SQ[c0] - 2.f * dot0;

  float dot1 = 0.f;
  {
    const float* crow = H + (size_t)c1 * HIDC;
    #pragma unroll 8
    for (int c4 = 0; c4 < HIDC / 4; ++c4) {
      f32x4 qv = *(const f32x4*)&qrow[wv][c4 * 4];
      f32x4 cv = *(const f32x4*)(crow + c4 * 4);
      dot1 += qv[0] * cv[0] + qv[1] * cv[1] + qv[2] * cv[2] + qv[3] * cv[3];
    }
  }
  float d1 = sqq + SQ[c1] - 2.f * dot1;

  float kf[KK2]; int ki[KK2];
  kf[0] = d0; ki[0] = c0;
  #pragma unroll
  for (int k = 1; k < KK2; ++k) { kf[k] = INFINITY; ki[k] = 0x7fffffff; }
  ins_lex<KK2>(kf, ki, d1, c1);
  #pragma unroll
  for (int dlt = 1; dlt <= 32; dlt <<= 1) {
    float of[KK2]; int oi[KK2];
    #pragma unroll
    for (int k = 0; k < KK2; ++k) { of[k] = __shfl_xor(kf[k], dlt, 64); oi[k] = __shfl_xor(ki[k], dlt, 64); }
    #pragma unroll
    for (int k = 0; k < KK2; ++k) ins_lex<KK2>(kf, ki, of[k], oi[k]);
  }
  if (lane == 0) {
    #pragma unroll
    for (int k = 0; k < KK2; ++k) idx_out[(size_t)q * KK2 + k] = ki[k];
  }
}

// ---------------------------------------------------------------- EdgeConv 2 (unchanged)
__global__ __launch_bounds__(256) void edgeconv2_kernel(
    const float* __restrict__ PQ, const int* __restrict__ knn,
    const float* __restrict__ W2, const float* __restrict__ b2,
    float* __restrict__ Out) {
  __shared__ float g1[4][KK2][OUTC2];
  __shared__ float w2s[2][8][OUTC2];
  const int tid  = threadIdx.x;
  const int lane = tid & 63;
  const int wv   = __builtin_amdgcn_readfirstlane(tid >> 6);
  const int p    = blockIdx.x * 4 + wv;
  const int ch0  = lane * 4;

  f32x4 pv = *(const f32x4*)&PQ[(size_t)p * PQC + ch0];
  #pragma unroll
  for (int e = 0; e < KK2; ++e) {
    int j = knn[p * KK2 + e];
    f32x4 qv = *(const f32x4*)&PQ[(size_t)j * PQC + OUTC2 + ch0];
    f32x4 g;
    #pragma unroll
    for (int c = 0; c < 4; ++c) g[c] = fmaxf(pv[c] + qv[c], 0.f);
    *(f32x4*)&g1[wv][e][ch0] = g;
  }

  {
    int r = tid >> 5, c0 = (tid & 31) * 8;
    *(f32x4*)&w2s[0][r][c0]     = *(const f32x4*)&W2[(size_t)r * OUTC2 + c0];
    *(f32x4*)&w2s[0][r][c0 + 4] = *(const f32x4*)&W2[(size_t)r * OUTC2 + c0 + 4];
  }
  __syncthreads();

  float acc2[KK2][4];
  #pragma unroll
  for (int e = 0; e < KK2; ++e)
    #pragma unroll
    for (int c = 0; c < 4; ++c) acc2[e][c] = 0.f;

  for (int c8 = 0; c8 < OUTC2 / 8; ++c8) {
    const int cur = c8 & 1;
    if (c8 + 1 < OUTC2 / 8) {
      int r = tid >> 5, c0 = (tid & 31) * 8;
      int gr = (c8 + 1) * 8 + r;
      *(f32x4*)&w2s[cur ^ 1][r][c0]     = *(const f32x4*)&W2[(size_t)gr * OUTC2 + c0];
      *(f32x4*)&w2s[cur ^ 1][r][c0 + 4] = *(const f32x4*)&W2[(size_t)gr * OUTC2 + c0 + 4];
    }
    f32x4 wreg[8];
    #pragma unroll
    for (int cc = 0; cc < 8; ++cc) wreg[cc] = *(const f32x4*)&w2s[cur][cc][ch0];
    #pragma unroll
    for (int e = 0; e < KK2; ++e) {
      f32x4 gv0 = *(const f32x4*)&g1[wv][e][c8 * 8];
      f32x4 gv1 = *(const f32x4*)&g1[wv][e][c8 * 8 + 4];
      #pragma unroll
      for (int cc = 0; cc < 4; ++cc)
        #pragma unroll
        for (int c = 0; c < 4; ++c) acc2[e][c] += gv0[cc] * wreg[cc][c];
      #pragma unroll
      for (int cc = 0; cc < 4; ++cc)
        #pragma unroll
        for (int c = 0; c < 4; ++c) acc2[e][c] += gv1[cc] * wreg[4 + cc][c];
    }
    __syncthreads();
  }

  f32x4 b2v = *(const f32x4*)&b2[ch0];
  f32x4 outv;
  #pragma unroll
  for (int c = 0; c < 4; ++c) {
    float m = -INFINITY;
    #pragma unroll
    for (int e = 0; e < KK2; ++e) m = fmaxf(m, acc2[e][c]);
    outv[c] = m + b2v[c];
  }
  *(f32x4*)&Out[(size_t)p * OUTC2 + ch0] = outv;
}

// ---------------------------------------------------------------- launch
extern "C" void kernel_launch(void* const* d_in, const int* in_sizes, int n_in,
                              void* d_out, int out_size, void* d_ws, size_t ws_size,
                              hipStream_t stream) {
  const float* x   = (const float*)d_in[0];
  const float* W1a = (const float*)d_in[1];
  const float* b1a = (const float*)d_in[2];
  const float* W1b = (const float*)d_in[3];
  const float* b1b = (const float*)d_in[4];
  const float* W2a = (const float*)d_in[5];
  const float* b2a = (const float*)d_in[6];
  const float* W2b = (const float*)d_in[7];
  const float* b2b = (const float*)d_in[8];
  float* out = (float*)d_out;

  float* h    = (float*)d_ws;                       // 4 MB
  float* sq2  = h + (size_t)NPTS * HIDC;
  int*   idx1 = (int*)(sq2 + NPTS);
  int*   idx2 = idx1 + (size_t)NPTS * KK1;
  unsigned short* Hhi = (unsigned short*)(idx2 + (size_t)NPTS * KK2);  // 2 MB
  unsigned short* Hlo = Hhi + (size_t)NPTS * HIDC;                     // 2 MB
  int*   pi2  = (int*)(Hlo + (size_t)NPTS * HIDC);  // 8192*128*4 = 4 MB
  float* Wc   = (float*)(pi2 + (size_t)NPTS * CPQ); // 256 KB
  float* PQ   = Wc + (size_t)HIDC * PQC;            // 16 MB
  // x4 aliases h's first 128KB: knn3 finishes before edgeconv1 writes h.
  float4* x4 = (float4*)h;

  pack_x_kernel<<<(NPTS + 255) / 256, 256, 0, stream>>>(x, x4);
  prep_w1_kernel<<<(HIDC * PQC) / 256, 256, 0, stream>>>(W2a, Wc);
  knn3_kernel<<<NPTS / 8, 256, 0, stream>>>(x4, idx1);
  edgeconv1_kernel<<<NPTS / 8, 256, 0, stream>>>(x, idx1, W1a, b1a, W1b, b1b,
                                                 h, Hhi, Hlo, sq2);
  gemm_pq_kernel<<<(NPTS / 32) * 8, 256, 0, stream>>>(h, Wc, b2a, PQ);
  knn128_filter_kernel<<<(NPTS / 64) * JSPLIT, 256, 0, stream>>>(Hhi, Hlo, sq2, pi2);
  knn_rescore_kernel<<<NPTS / 4, 256, 0, stream>>>(h, sq2, pi2, idx2);
  edgeconv2_kernel<<<NPTS / 4, 256, 0, stream>>>(PQ, idx2, W2b, b2b, out);
}

// Round 11
// 420.981 us; speedup vs baseline: 1.8769x; 1.2717x over previous
//
#include <hip/hip_runtime.h>
#include <math.h>

constexpr int NPTS  = 8192;
constexpr int HIDC  = 128;
constexpr int OUTC2 = 256;
constexpr int PQC   = 512;
constexpr int KK1   = 16;
constexpr int KK2   = 8;

typedef __attribute__((ext_vector_type(8))) short short8;
typedef __attribute__((ext_vector_type(4))) float f32x4;

__device__ __forceinline__ f32x4 mfma16(short8 a, short8 b, f32x4 c) {
  return __builtin_amdgcn_mfma_f32_16x16x32_bf16(a, b, c, 0, 0, 0);
}

__device__ __forceinline__ void async_ld16(void* lds, const void* g) {
  __builtin_amdgcn_global_load_lds(
      (const __attribute__((address_space(1))) unsigned int*)g,
      (__attribute__((address_space(3))) unsigned int*)lds, 16, 0, 0);
}

// packed-key insert: keys unique (j embedded) -> strict < is exact lex.
template <int K>
__device__ __forceinline__ void ins_u(unsigned (&kk)[K], unsigned v) {
  if (v < kk[K - 1]) {
    kk[K - 1] = v;
    #pragma unroll
    for (int p = K - 1; p > 0; --p) {
      unsigned a = kk[p - 1], b = kk[p];
      kk[p - 1] = a < b ? a : b;
      kk[p]     = a < b ? b : a;
    }
  }
}

// lexicographic (d, idx) insert — exact fp32 merging.
template <int K>
__device__ __forceinline__ void ins_lex(float (&kf)[K], int (&ki)[K], float v, int j) {
  bool ins = (v < kf[K - 1]) || (v == kf[K - 1] && j < ki[K - 1]);
  if (ins) {
    kf[K - 1] = v; ki[K - 1] = j;
    #pragma unroll
    for (int p = K - 1; p > 0; --p) {
      float fa = kf[p - 1], fb = kf[p];
      int   ia = ki[p - 1], ib = ki[p];
      bool sw = (fb < fa) || (fb == fa && ib < ia);
      kf[p - 1] = sw ? fb : fa; ki[p - 1] = sw ? ib : ia;
      kf[p]     = sw ? fa : fb; ki[p]     = sw ? ia : ib;
    }
  }
}

__device__ __forceinline__ unsigned short bf16_rn(float x) {
  unsigned int u = __float_as_uint(x);
  unsigned int r = u + 0x7fffu + ((u >> 16) & 1u);
  return (unsigned short)(r >> 16);
}

// ---------------------------------------------------------------- pack x
__global__ void pack_x_kernel(const float* __restrict__ x, float4* __restrict__ x4) {
  int i = blockIdx.x * blockDim.x + threadIdx.x;
  if (i < NPTS) {
    float a = x[3 * i], b = x[3 * i + 1], c = x[3 * i + 2];
    x4[i] = make_float4(a, b, c, a * a + b * b + c * c);
  }
}

// ---------------------------------------------------------------- Wc = [Wl-Wh | Wh] for layer2 stage1
__global__ void prep_w1_kernel(const float* __restrict__ W1, float* __restrict__ Wc) {
  int idx = blockIdx.x * 256 + threadIdx.x;    // 128*512
  int k = idx >> 9, c = idx & 511;
  float wh = W1[(size_t)(HIDC + k) * OUTC2 + (c & 255)];
  Wc[idx] = (c < OUTC2) ? (W1[(size_t)k * OUTC2 + c] - wh) : wh;
}

// ---------------------------------------------------------------- KNN1 (C=3, K=16)
// Wave per query. Per-lane u32-key top-8 filter over its 128-j stream (no
// cross-lane ops in the scan), then per-lane exact fp32 rescore of its 8,
// then 16-pop wave heads-merge (exact lex) -> exact top-16 SET (order-free;
// ec1 max-pool is order-invariant; R6 also wrote unordered and passed).
__global__ __launch_bounds__(256) void knn3_kernel(const float4* __restrict__ X4,
                                                   int* __restrict__ idx_out) {
  const int tid  = threadIdx.x;
  const int lane = tid & 63;
  const int wv   = __builtin_amdgcn_readfirstlane(tid >> 6);
  const int q    = blockIdx.x * 4 + wv;

  const float4 qv = X4[q];

  unsigned kk[KK2];
  #pragma unroll
  for (int k = 0; k < KK2; ++k) kk[k] = 0xFFFFFFFFu;

  for (int c = 0; c < NPTS / 64; ++c) {
    const int j = c * 64 + lane;
    float4 pj = X4[j];
    float d = fmaxf(qv.w + pj.w - 2.f * (qv.x * pj.x + qv.y * pj.y + qv.z * pj.z), 0.f);
    unsigned key = (__float_as_uint(d) & 0xFFFFE000u) | (unsigned)j;
    if (j == q) key = 0xFFFFFFFFu;
    ins_u<KK2>(kk, key);
  }

  // exact fp32 rescore of the 8 kept candidates (same formula as R6-passing)
  float kf[KK2]; int kj[KK2];
  #pragma unroll
  for (int k = 0; k < KK2; ++k) { kf[k] = INFINITY; kj[k] = 0x7fffffff; }
  #pragma unroll
  for (int k = 0; k < KK2; ++k) {
    int j = (int)(kk[k] & 0x1FFFu);
    float4 pj = X4[j];
    float d = qv.w + pj.w - 2.f * (qv.x * pj.x + qv.y * pj.y + qv.z * pj.z);
    if (kk[k] == 0xFFFFFFFFu) { d = INFINITY; j = 0x7fffffff; }  // defensive
    ins_lex<KK2>(kf, kj, d, j);
  }

  // heads-merge: 16 pops of wave-wide lex-argmin (pairs unique via j)
  #pragma unroll
  for (int k = 0; k < KK1; ++k) {
    float mf = kf[0]; int mj = kj[0];
    #pragma unroll
    for (int m = 1; m <= 32; m <<= 1) {
      float of = __shfl_xor(mf, m, 64);
      int   oj = __shfl_xor(mj, m, 64);
      bool g = (of < mf) || (of == mf && oj < mj);
      mf = g ? of : mf; mj = g ? oj : mj;
    }
    const bool won = (kf[0] == mf) && (kj[0] == mj);
    if (won) {
      idx_out[(size_t)q * KK1 + k] = mj;
      #pragma unroll
      for (int p = 0; p < KK2 - 1; ++p) { kf[p] = kf[p + 1]; kj[p] = kj[p + 1]; }
      kf[KK2 - 1] = INFINITY; kj[KK2 - 1] = 0x7fffffff;
    }
  }
}

// ---------------------------------------------------------------- EdgeConv 1 (unchanged)
__global__ __launch_bounds__(256) void edgeconv1_kernel(
    const float* __restrict__ X, const int* __restrict__ knn,
    const float* __restrict__ W1, const float* __restrict__ b1,
    const float* __restrict__ W2, const float* __restrict__ b2,
    float* __restrict__ H, unsigned short* __restrict__ Hhi,
    unsigned short* __restrict__ Hlo, float* __restrict__ SQ2) {
  __shared__ float h1[8][KK1][HIDC];
  __shared__ float xjs[8][KK1][3];
  __shared__ float xis[8][3];
  const int tid  = threadIdx.x;
  const int lane = tid & 63;
  const int wv   = __builtin_amdgcn_readfirstlane(tid >> 6);
  const int half = lane >> 5;
  const int hl   = lane & 31;
  const int lp   = wv * 2 + half;
  const int p    = blockIdx.x * 8 + lp;
  const int ch0  = hl * 4;

  if (hl < KK1) {
    int j = knn[p * KK1 + hl];
    xjs[lp][hl][0] = X[3 * j]; xjs[lp][hl][1] = X[3 * j + 1]; xjs[lp][hl][2] = X[3 * j + 2];
  } else if (hl < KK1 + 3) {
    xis[lp][hl - KK1] = X[3 * p + hl - KK1];
  }
  __syncthreads();

  f32x4 w1r[6];
  #pragma unroll
  for (int c = 0; c < 6; ++c) w1r[c] = *(const f32x4*)&W1[c * HIDC + ch0];
  f32x4 b1v = *(const f32x4*)&b1[ch0];
  const float xi0 = xis[lp][0], xi1 = xis[lp][1], xi2 = xis[lp][2];
  f32x4 base;
  #pragma unroll
  for (int c = 0; c < 4; ++c)
    base[c] = b1v[c] + xi0 * w1r[0][c] + xi1 * w1r[1][c] + xi2 * w1r[2][c];
  #pragma unroll
  for (int e = 0; e < KK1; ++e) {
    float dx = xjs[lp][e][0] - xi0, dy = xjs[lp][e][1] - xi1, dz = xjs[lp][e][2] - xi2;
    f32x4 v;
    #pragma unroll
    for (int c = 0; c < 4; ++c)
      v[c] = fmaxf(base[c] + dx * w1r[3][c] + dy * w1r[4][c] + dz * w1r[5][c], 0.f);
    *(f32x4*)&h1[lp][e][ch0] = v;
  }
  __syncthreads();

  float acc[KK1][4];
  #pragma unroll
  for (int e = 0; e < KK1; ++e)
    #pragma unroll
    for (int c = 0; c < 4; ++c) acc[e][c] = 0.f;
  for (int c4 = 0; c4 < HIDC / 4; ++c4) {
    f32x4 w2r[4];
    #pragma unroll
    for (int cc = 0; cc < 4; ++cc)
      w2r[cc] = *(const f32x4*)&W2[(c4 * 4 + cc) * HIDC + ch0];
    #pragma unroll
    for (int e = 0; e < KK1; ++e) {
      f32x4 hv = *(const f32x4*)&h1[lp][e][c4 * 4];
      #pragma unroll
      for (int cc = 0; cc < 4; ++cc)
        #pragma unroll
        for (int c = 0; c < 4; ++c) acc[e][c] += hv[cc] * w2r[cc][c];
    }
  }
  f32x4 b2v = *(const f32x4*)&b2[ch0];
  f32x4 outv;
  #pragma unroll
  for (int c = 0; c < 4; ++c) {
    float m = -INFINITY;
    #pragma unroll
    for (int e = 0; e < KK1; ++e) m = fmaxf(m, acc[e][c]);
    outv[c] = m + b2v[c];
  }
  *(f32x4*)&H[(size_t)p * HIDC + ch0] = outv;

  unsigned short hb[4], lb[4];
  #pragma unroll
  for (int c = 0; c < 4; ++c) {
    hb[c] = bf16_rn(outv[c]);
    float fh = __uint_as_float(((unsigned int)hb[c]) << 16);
    lb[c] = bf16_rn(outv[c] - fh);
  }
  *(ushort4*)&Hhi[(size_t)p * HIDC + ch0] = make_ushort4(hb[0], hb[1], hb[2], hb[3]);
  *(ushort4*)&Hlo[(size_t)p * HIDC + ch0] = make_ushort4(lb[0], lb[1], lb[2], lb[3]);

  float s = outv[0]*outv[0] + outv[1]*outv[1] + outv[2]*outv[2] + outv[3]*outv[3];
  #pragma unroll
  for (int m = 1; m <= 16; m <<= 1) s += __shfl_xor(s, m, 64);
  if (hl == 0) SQ2[p] = s;
}

// ---------------------------------------------------------------- PQ = H @ Wc (+b1 on P half)
__global__ __launch_bounds__(256) void gemm_pq_kernel(
    const float* __restrict__ H, const float* __restrict__ Wc,
    const float* __restrict__ b1, float* __restrict__ PQ) {
  __shared__ float Hs[32][HIDC];
  const int tid = threadIdx.x;
  const int rb  = blockIdx.x >> 3;
  const int cb  = blockIdx.x & 7;
  const int col = cb * 64 + (tid & 63);
  const int rg  = tid >> 6;

  #pragma unroll
  for (int u = 0; u < 4; ++u) {
    int idx = u * 256 + tid;
    int r = idx >> 5, k4 = idx & 31;
    *(f32x4*)&Hs[r][k4 * 4] = *(const f32x4*)&H[(size_t)(rb * 32 + r) * HIDC + k4 * 4];
  }
  __syncthreads();

  float acc[8] = {};
  for (int k = 0; k < HIDC; ++k) {
    float w = Wc[(size_t)k * PQC + col];
    #pragma unroll
    for (int i = 0; i < 8; ++i) acc[i] += Hs[rg * 8 + i][k] * w;
  }
  const float bb = (col < OUTC2) ? b1[col] : 0.f;
  #pragma unroll
  for (int i = 0; i < 8; ++i)
    PQ[(size_t)(rb * 32 + rg * 8 + i) * PQC + col] = acc[i] + bb;
}

// ---------------------------------------------------------------- KNN2 filter (unchanged from R10)
constexpr int JSPLIT = 16;
constexpr int JPB2   = NPTS / JSPLIT;   // 512 rows per split
constexpr int NCH    = JPB2 / 16;       // 32 chunks of 16 rows
constexpr int CPQ    = JSPLIT * KK2;    // 128 candidates per query

__global__ __launch_bounds__(256) void knn128_filter_kernel(
    const unsigned short* __restrict__ Hhi, const unsigned short* __restrict__ Hlo,
    const float* __restrict__ SQ, int* __restrict__ pi2) {
  __shared__ __align__(16) unsigned short As[2][2][16 * HIDC];
  const int tid  = threadIdx.x;
  const int lane = tid & 63;
  const int wv   = __builtin_amdgcn_readfirstlane(tid >> 6);
  const int qb   = blockIdx.x >> 4;
  const int js   = blockIdx.x & 15;
  const int col  = lane & 15;
  const int kg   = lane >> 4;
  const int qg   = qb * 64 + wv * 16 + col;

  short8 qhi[4], qlo[4];
  #pragma unroll
  for (int s = 0; s < 4; ++s) {
    const size_t o = (size_t)qg * HIDC + s * 32 + kg * 8;
    qhi[s] = *reinterpret_cast<const short8*>(Hhi + o);
    qlo[s] = *reinterpret_cast<const short8*>(Hlo + o);
  }
  const float sqq = SQ[qg];

  unsigned kk[KK2];
  #pragma unroll
  for (int k = 0; k < KK2; ++k) kk[k] = 0xFFFFFFFFu;

  const int jbase = js * JPB2;

  const int srow = 4 * wv + (lane >> 4);
  const int sslt = (lane & 15) ^ (srow & 7);
  auto stage = [&](int buf, int ch) {
    const size_t gofs = (size_t)(jbase + ch * 16 + srow) * HIDC + sslt * 8;
    async_ld16((char*)&As[buf][0][0] + wv * 1024, Hhi + gofs);
    async_ld16((char*)&As[buf][1][0] + wv * 1024, Hlo + gofs);
  };

  stage(0, 0);
  asm volatile("s_waitcnt vmcnt(0)" ::: "memory");
  __syncthreads();

  for (int ch = 0; ch < NCH; ++ch) {
    const int cur = ch & 1;
    if (ch + 1 < NCH) stage(cur ^ 1, ch + 1);

    const int jb = jbase + ch * 16;
    short8 ahi[4], alo[4];
    const int rowb = col * 256;
    #pragma unroll
    for (int s = 0; s < 4; ++s) {
      const int sl = ((s * 4 + kg) ^ (col & 7)) * 16;
      ahi[s] = *(const short8*)((const char*)&As[cur][0][0] + rowb + sl);
      alo[s] = *(const short8*)((const char*)&As[cur][1][0] + rowb + sl);
    }
    f32x4 sqjv = *reinterpret_cast<const f32x4*>(SQ + jb + kg * 4);

    f32x4 acc = {0.f, 0.f, 0.f, 0.f};
    #pragma unroll
    for (int s = 0; s < 4; ++s) {
      acc = mfma16(ahi[s], qhi[s], acc);
      acc = mfma16(ahi[s], qlo[s], acc);
      acc = mfma16(alo[s], qhi[s], acc);
    }
    #pragma unroll
    for (int r = 0; r < 4; ++r) {
      const int jg = jb + kg * 4 + r;
      float d = fmaxf(sqq + sqjv[r] - 2.f * acc[r], 0.f);
      unsigned key = (__float_as_uint(d) & 0xFFFFE000u) | (unsigned)jg;
      if (jg == qg) key = 0xFFFFFFFFu;
      ins_u<KK2>(kk, key);
    }
    asm volatile("s_waitcnt vmcnt(0)" ::: "memory");
    __syncthreads();
  }

  #pragma unroll
  for (int dlt = 16; dlt <= 32; dlt <<= 1) {
    unsigned ok[KK2];
    #pragma unroll
    for (int k = 0; k < KK2; ++k) ok[k] = __shfl_xor((int)kk[k], dlt, 64);
    #pragma unroll
    for (int k = 0; k < KK2; ++k) ins_u<KK2>(kk, ok[k]);
  }
  if (lane < 16) {
    const size_t base = (size_t)qg * CPQ + js * KK2;
    #pragma unroll
    for (int k = 0; k < KK2; ++k) pi2[base + k] = (int)(kk[k] & 0x1FFFu);
  }
}

// ---------------------------------------------------------------- exact fp32 rescore (unchanged)
__global__ __launch_bounds__(256) void knn_rescore_kernel(
    const float* __restrict__ H, const float* __restrict__ SQ,
    const int* __restrict__ pi2, int* __restrict__ idx_out) {
  __shared__ float qrow[4][HIDC];
  const int tid  = threadIdx.x;
  const int wv   = tid >> 6;
  const int lane = tid & 63;
  const int q0   = blockIdx.x * 4;
  const int q    = q0 + wv;
  for (int u = tid; u < 4 * HIDC; u += 256)
    qrow[u >> 7][u & 127] = H[(size_t)(q0 + (u >> 7)) * HIDC + (u & 127)];
  __syncthreads();

  const int c0 = pi2[(size_t)q * CPQ + lane];
  const int c1 = pi2[(size_t)q * CPQ + 64 + lane];
  const float sqq = SQ[q];

  float dot0 = 0.f;
  {
    const float* crow = H + (size_t)c0 * HIDC;
    #pragma unroll 8
    for (int c4 = 0; c4 < HIDC / 4; ++c4) {
      f32x4 qv = *(const f32x4*)&qrow[wv][c4 * 4];
      f32x4 cv = *(const f32x4*)(crow + c4 * 4);
      dot0 += qv[0] * cv[0] + qv[1] * cv[1] + qv[2] * cv[2] + qv[3] * cv[3];
    }
  }
  float d0 = sqq + SQ[c0] - 2.f * dot0;

  float dot1 = 0.f;
  {
    const float* crow = H + (size_t)c1 * HIDC;
    #pragma unroll 8
    for (int c4 = 0; c4 < HIDC / 4; ++c4) {
      f32x4 qv = *(const f32x4*)&qrow[wv][c4 * 4];
      f32x4 cv = *(const f32x4*)(crow + c4 * 4);
      dot1 += qv[0] * cv[0] + qv[1] * cv[1] + qv[2] * cv[2] + qv[3] * cv[3];
    }
  }
  float d1 = sqq + SQ[c1] - 2.f * dot1;

  float kf[KK2]; int ki[KK2];
  kf[0] = d0; ki[0] = c0;
  #pragma unroll
  for (int k = 1; k < KK2; ++k) { kf[k] = INFINITY; ki[k] = 0x7fffffff; }
  ins_lex<KK2>(kf, ki, d1, c1);
  #pragma unroll
  for (int dlt = 1; dlt <= 32; dlt <<= 1) {
    float of[KK2]; int oi[KK2];
    #pragma unroll
    for (int k = 0; k < KK2; ++k) { of[k] = __shfl_xor(kf[k], dlt, 64); oi[k] = __shfl_xor(ki[k], dlt, 64); }
    #pragma unroll
    for (int k = 0; k < KK2; ++k) ins_lex<KK2>(kf, ki, of[k], oi[k]);
  }
  if (lane == 0) {
    #pragma unroll
    for (int k = 0; k < KK2; ++k) idx_out[(size_t)q * KK2 + k] = ki[k];
  }
}

// ---------------------------------------------------------------- EdgeConv 2 (unchanged)
__global__ __launch_bounds__(256) void edgeconv2_kernel(
    const float* __restrict__ PQ, const int* __restrict__ knn,
    const float* __restrict__ W2, const float* __restrict__ b2,
    float* __restrict__ Out) {
  __shared__ float g1[4][KK2][OUTC2];
  __shared__ float w2s[2][8][OUTC2];
  const int tid  = threadIdx.x;
  const int lane = tid & 63;
  const int wv   = __builtin_amdgcn_readfirstlane(tid >> 6);
  const int p    = blockIdx.x * 4 + wv;
  const int ch0  = lane * 4;

  f32x4 pv = *(const f32x4*)&PQ[(size_t)p * PQC + ch0];
  #pragma unroll
  for (int e = 0; e < KK2; ++e) {
    int j = knn[p * KK2 + e];
    f32x4 qv = *(const f32x4*)&PQ[(size_t)j * PQC + OUTC2 + ch0];
    f32x4 g;
    #pragma unroll
    for (int c = 0; c < 4; ++c) g[c] = fmaxf(pv[c] + qv[c], 0.f);
    *(f32x4*)&g1[wv][e][ch0] = g;
  }

  {
    int r = tid >> 5, c0 = (tid & 31) * 8;
    *(f32x4*)&w2s[0][r][c0]     = *(const f32x4*)&W2[(size_t)r * OUTC2 + c0];
    *(f32x4*)&w2s[0][r][c0 + 4] = *(const f32x4*)&W2[(size_t)r * OUTC2 + c0 + 4];
  }
  __syncthreads();

  float acc2[KK2][4];
  #pragma unroll
  for (int e = 0; e < KK2; ++e)
    #pragma unroll
    for (int c = 0; c < 4; ++c) acc2[e][c] = 0.f;

  for (int c8 = 0; c8 < OUTC2 / 8; ++c8) {
    const int cur = c8 & 1;
    if (c8 + 1 < OUTC2 / 8) {
      int r = tid >> 5, c0 = (tid & 31) * 8;
      int gr = (c8 + 1) * 8 + r;
      *(f32x4*)&w2s[cur ^ 1][r][c0]     = *(const f32x4*)&W2[(size_t)gr * OUTC2 + c0];
      *(f32x4*)&w2s[cur ^ 1][r][c0 + 4] = *(const f32x4*)&W2[(size_t)gr * OUTC2 + c0 + 4];
    }
    f32x4 wreg[8];
    #pragma unroll
    for (int cc = 0; cc < 8; ++cc) wreg[cc] = *(const f32x4*)&w2s[cur][cc][ch0];
    #pragma unroll
    for (int e = 0; e < KK2; ++e) {
      f32x4 gv0 = *(const f32x4*)&g1[wv][e][c8 * 8];
      f32x4 gv1 = *(const f32x4*)&g1[wv][e][c8 * 8 + 4];
      #pragma unroll
      for (int cc = 0; cc < 4; ++cc)
        #pragma unroll
        for (int c = 0; c < 4; ++c) acc2[e][c] += gv0[cc] * wreg[cc][c];
      #pragma unroll
      for (int cc = 0; cc < 4; ++cc)
        #pragma unroll
        for (int c = 0; c < 4; ++c) acc2[e][c] += gv1[cc] * wreg[4 + cc][c];
    }
    __syncthreads();
  }

  f32x4 b2v = *(const f32x4*)&b2[ch0];
  f32x4 outv;
  #pragma unroll
  for (int c = 0; c < 4; ++c) {
    float m = -INFINITY;
    #pragma unroll
    for (int e = 0; e < KK2; ++e) m = fmaxf(m, acc2[e][c]);
    outv[c] = m + b2v[c];
  }
  *(f32x4*)&Out[(size_t)p * OUTC2 + ch0] = outv;
}

// ---------------------------------------------------------------- launch
extern "C" void kernel_launch(void* const* d_in, const int* in_sizes, int n_in,
                              void* d_out, int out_size, void* d_ws, size_t ws_size,
                              hipStream_t stream) {
  const float* x   = (const float*)d_in[0];
  const float* W1a = (const float*)d_in[1];
  const float* b1a = (const float*)d_in[2];
  const float* W1b = (const float*)d_in[3];
  const float* b1b = (const float*)d_in[4];
  const float* W2a = (const float*)d_in[5];
  const float* b2a = (const float*)d_in[6];
  const float* W2b = (const float*)d_in[7];
  const float* b2b = (const float*)d_in[8];
  float* out = (float*)d_out;

  float* h    = (float*)d_ws;                       // 4 MB
  float* sq2  = h + (size_t)NPTS * HIDC;
  int*   idx1 = (int*)(sq2 + NPTS);
  int*   idx2 = idx1 + (size_t)NPTS * KK1;
  unsigned short* Hhi = (unsigned short*)(idx2 + (size_t)NPTS * KK2);  // 2 MB
  unsigned short* Hlo = Hhi + (size_t)NPTS * HIDC;                     // 2 MB
  int*   pi2  = (int*)(Hlo + (size_t)NPTS * HIDC);  // 4 MB
  float* Wc   = (float*)(pi2 + (size_t)NPTS * CPQ); // 256 KB
  float* PQ   = Wc + (size_t)HIDC * PQC;            // 16 MB
  // x4 aliases h's first 128KB: knn3 finishes before edgeconv1 writes h.
  float4* x4 = (float4*)h;

  pack_x_kernel<<<(NPTS + 255) / 256, 256, 0, stream>>>(x, x4);
  prep_w1_kernel<<<(HIDC * PQC) / 256, 256, 0, stream>>>(W2a, Wc);
  knn3_kernel<<<NPTS / 4, 256, 0, stream>>>(x4, idx1);
  edgeconv1_kernel<<<NPTS / 8, 256, 0, stream>>>(x, idx1, W1a, b1a, W1b, b1b,
                                                 h, Hhi, Hlo, sq2);
  gemm_pq_kernel<<<(NPTS / 32) * 8, 256, 0, stream>>>(h, Wc, b2a, PQ);
  knn128_filter_kernel<<<(NPTS / 64) * JSPLIT, 256, 0, stream>>>(Hhi, Hlo, sq2, pi2);
  knn_rescore_kernel<<<NPTS / 4, 256, 0, stream>>>(h, sq2, pi2, idx2);
  edgeconv2_kernel<<<NPTS / 4, 256, 0, stream>>>(PQ, idx2, W2b, b2b, out);
}